// Round 11
// baseline (664.181 us; speedup 1.0000x reference)
//
#include <hip/hip_runtime.h>
#include <hip/hip_cooperative_groups.h>
#include <cmath>

namespace cg = cooperative_groups;

#define PI_F 3.14159265358979323846f
#define NTOK 128
#define NPIX 16384
#define NHEADS 16

__device__ __forceinline__ void block_reduce2(float& a, float& b){
  __shared__ float sa[4], sb[4];
  __syncthreads();
  for (int o=32;o>0;o>>=1){ a += __shfl_down(a,o); b += __shfl_down(b,o); }
  int w = threadIdx.x>>6, l = threadIdx.x&63;
  if (l==0){ sa[w]=a; sb[w]=b; }
  __syncthreads();
  a = sa[0]+sa[1]+sa[2]+sa[3];
  b = sb[0]+sb[1]+sb[2]+sb[3];
}

__device__ __forceinline__ float block_reduce1(float a){
  __shared__ float sa[4];
  __syncthreads();
  for (int o=32;o>0;o>>=1) a += __shfl_down(a,o);
  int w = threadIdx.x>>6, l = threadIdx.x&63;
  if (l==0) sa[w]=a;
  __syncthreads();
  return sa[0]+sa[1]+sa[2]+sa[3];
}

__device__ __forceinline__ float gelu_f(float y){
  return 0.5f*y*(1.f + erff(y*0.70710678118f));
}

// ---- per-token scalars: pstat0 is 8-slab; pstatA/B/C are 16-slab -----------
__device__ __forceinline__ void affine_from(const float* __restrict__ ps, float g, float bb, int t,
                                            float& a, float& b0){
  float sum=0.f,sq=0.f;
  #pragma unroll
  for (int s=0;s<8;s++){ const float* p=ps+((size_t)t*8+s)*2; sum+=p[0]; sq+=p[1]; }
  const float iN=1.f/NPIX;
  float mu=sum*iN, var=sq*iN-mu*mu;
  a=rsqrtf(var+1e-5f)*g;
  b0=bb-mu*a;
}
__device__ __forceinline__ void scalA_from(const float* __restrict__ psA, float ag, float n2g, int t,
                                           float& muZ, float& aA, float& a0){
  float sum=0.f,sq=0.f;
  #pragma unroll
  for (int s=0;s<16;s++){ const float* p=psA+((size_t)t*16+s)*2; sum+=p[0]; sq+=p[1]; }
  const float iN=1.f/NPIX;
  muZ=sum*iN; float var=sq*iN-muZ*muZ;
  float inv=rsqrtf(var+1e-5f);
  aA=inv*ag;
  float var2=aA*aA*var;
  a0=aA*rsqrtf(var2+1e-5f)*n2g;
}
__device__ __forceinline__ void scalB_from(const float* __restrict__ psB, float mng1, int t,
                                           float& mu1, float& c1){
  float sum=0.f,sq=0.f;
  #pragma unroll
  for (int s=0;s<16;s++){ const float* p=psB+((size_t)t*16+s)*2; sum+=p[0]; sq+=p[1]; }
  const float iN=1.f/NPIX;
  mu1=sum*iN; float var=sq*iN-mu1*mu1;
  c1=rsqrtf(var+1e-5f)*mng1;
}
__device__ __forceinline__ void scalC_from(const float* __restrict__ psC, float mng2, float K, float sw,
                                           float outg, int t,
                                           float& mu2f, float& c2, float& mu3, float& c3){
  float sf=0.f,sfsq=0.f,sm=0.f,smsq=0.f,sx=0.f;
  #pragma unroll
  for (int s=0;s<16;s++){
    const float* p=psC+((size_t)t*16+s)*5;
    sf+=p[0]; sfsq+=p[1]; sm+=p[2]; smsq+=p[3]; sx+=p[4];
  }
  const float iN=1.f/NPIX;
  mu2f=sf*iN; float var2=sfsq*iN-mu2f*mu2f;
  c2=rsqrtf(var2+1e-5f)*mng2;
  float Em1=sm*iN, Em1sq=smsq*iN, Exm=sx*iN;
  float Em2=K+sw*Em1;
  float Em2sq = c2*c2*var2 + sw*sw*Em1sq + K*K
              + 2.f*c2*sw*(Exm - mu2f*Em1) + 2.f*K*sw*Em1;
  float var_m2=Em2sq-Em2*Em2;
  mu3=Em2;
  c3=rsqrtf(var_m2+1e-5f)*outg;
}

// ---- slab stats of x (8 slabs) ---------------------------------------------
__global__ __launch_bounds__(256) void k_stats0(const float* __restrict__ x, float* __restrict__ pstat){
  int t=blockIdx.x, slab=blockIdx.y;
  const float* xs = x + (size_t)t*NPIX + slab*2048;
  float sum=0.f, sq=0.f;
  for (int i=threadIdx.x;i<2048;i+=256){ float v=xs[i]; sum+=v; sq+=v*v; }
  block_reduce2(sum,sq);
  if (threadIdx.x==0){ float* o=pstat+((size_t)t*8+slab)*2; o[0]=sum; o[1]=sq; }
}

// ---- Column DFT of tn (affine-folded inline), 16 rows per block ------------
__global__ __launch_bounds__(256) void k_colfft33(const float* __restrict__ x, const float* __restrict__ pstat0,
                          const float* __restrict__ n1g, const float* __restrict__ n1b,
                          float* __restrict__ A){
  __shared__ float rows[16*128];
  __shared__ float tw[128][2];
  int base = blockIdx.x*16;
  int t = base>>7;
  float a,b0; affine_from(pstat0, n1g[0], n1b[0], t, a, b0);
  for (int i=threadIdx.x;i<2048;i+=256) rows[i] = a*x[(size_t)base*128 + i] + b0;
  for (int p=threadIdx.x;p<128;p+=256){ float sn,cs; sincosf(-(2.f*PI_F/128.f)*(float)p,&sn,&cs); tw[p][0]=cs; tw[p][1]=sn; }
  __syncthreads();
  for (int e=threadIdx.x;e<16*33;e+=256){
    int r=e/33, c=e%33;
    const float* rp=rows+r*128;
    float re=0.f, im=0.f;
    for (int w=0;w<128;w++){
      int p=(c*w)&127;
      float v=rp[w];
      re+=v*tw[p][0]; im+=v*tw[p][1];
    }
    float* o=A+((size_t)(base+r)*33+c)*2; o[0]=re; o[1]=im;
  }
}

// ---- Row DFT -> 64x33 spectrum, column-group parallel ----------------------
__global__ __launch_bounds__(256) void k_rowfft64(const float* __restrict__ A,
                          float* __restrict__ X64, float* __restrict__ X64h){
  int s=blockIdx.x, cg2=blockIdx.y;
  int c0=cg2*11;
  __shared__ float a[128][11][2];
  __shared__ float S[64][11][2];
  __shared__ float tw[128][2];
  for (int i=threadIdx.x;i<128*22;i+=256){
    int r=i/22, q=i%22;
    a[r][q>>1][q&1] = A[((size_t)(s*128+r)*33 + c0)*2 + q];
  }
  for (int p=threadIdx.x;p<128;p+=256){ float sn,cs; sincosf(-(2.f*PI_F/128.f)*(float)p,&sn,&cs); tw[p][0]=cs; tw[p][1]=sn; }
  __syncthreads();
  const float sc=1.f/16384.f;
  for (int e=threadIdx.x;e<64*11;e+=256){
    int i2=e/11, cl=e%11;
    int r=(i2<32)? i2 : i2+64;
    float re=0.f, im=0.f;
    for (int h=0;h<128;h++){
      int p=(r*h)&127;
      float cs=tw[p][0], sn=tw[p][1];
      float ar=a[h][cl][0], ai=a[h][cl][1];
      re+=ar*cs-ai*sn; im+=ar*sn+ai*cs;
    }
    S[i2][cl][0]=re*sc; S[i2][cl][1]=im*sc;
  }
  __syncthreads();
  for (int e=threadIdx.x;e<64*11;e+=256){
    int r=e/11, cl=e%11; int c=c0+cl;
    float vr=S[r][cl][0], vi=S[r][cl][1];
    float* o=X64+((size_t)s*(64*33)+r*33+c)*2; o[0]=vr; o[1]=vi;
    float hr=vr, hi=vi;
    if (c==0 || c==32){
      int pr=(64-r)&63;
      hr=0.5f*(vr+S[pr][cl][0]);
      hi=0.5f*(vi-S[pr][cl][1]);
    }
    float* oh=X64h+((size_t)s*(64*33)+r*33+c)*2; oh[0]=hr; oh[1]=hi;
  }
}

// ---- merged Ue + ZYw (independent stages, block-range branch) --------------
__global__ __launch_bounds__(256) void k_UeZYw(const float* __restrict__ X64, const float* __restrict__ X64h,
    const float* __restrict__ qw, const float* __restrict__ qsw,
    const float* __restrict__ kw, const float* __restrict__ ksw,
    const float* __restrict__ value_w, const float* __restrict__ vsw, const float* __restrict__ vsb,
    const float* __restrict__ proj_w, const float* __restrict__ psw,
    float* __restrict__ Zq, float* __restrict__ Zk, float* __restrict__ Yw,
    float* __restrict__ Ue){
  __shared__ float sh[4224];
  int bx=blockIdx.x;
  if (bx<2048){
    int t=bx>>4, h=bx&15;
    float* Xs = sh;
    float2* xh0 = (float2*)(sh+1092);
    for (int e=threadIdx.x;e<544;e+=256){
      int j=e/17, c=e%17;
      int i2=(j<16)? j : (j+32);
      const float* xp = X64 + ((size_t)t*(64*33) + i2*33 + c)*2;
      Xs[e*2]=xp[0]; Xs[e*2+1]=xp[1];
    }
    if (threadIdx.x<17){
      int j=threadIdx.x;
      int r=(j<=8)? j : j+47;
      const float* hp = X64h + ((size_t)t*(64*33) + r*33)*2;
      xh0[j]=make_float2(hp[0],hp[1]);
    }
    __syncthreads();
    float aq=qsw[h], ak=ksw[h];
    for (int e=threadIdx.x;e<306;e+=256){
      int side=e/153, m=e%153;
      int j=m/9, c=m%9;
      int jj=(j<=8)? j : j+15;
      const float* W = side? kw : qw;
      float a = side? ak : aq;
      float prx=0.f, pry=0.f;
      if (j!=8){
        int jw=(j<8)? j : j-1;
        const float* wp = W + ((size_t)(h*16+jw)*9 + c)*2;
        float xrr=Xs[(jj*17+c)*2], xri=Xs[(jj*17+c)*2+1];
        prx = wp[0]*xrr - wp[1]*xri;
        pry = wp[0]*xri + wp[1]*xrr;
      }
      float Vx=prx, Vy=pry;
      if (c==0){
        int jp = (j==0)? 0 : 17-j;
        float ppx=0.f, ppy=0.f;
        if (jp!=8){
          int jw2=(jp<8)? jp : jp-1;
          const float* wp2 = W + ((size_t)(h*16+jw2)*9)*2;
          int jj2=(jp<=8)? jp : jp+15;
          float x2r=Xs[(jj2*17)*2], x2i=Xs[(jj2*17)*2+1];
          ppx = wp2[0]*x2r - wp2[1]*x2i;
          ppy = wp2[0]*x2i + wp2[1]*x2r;
        }
        Vx = 0.5f*(prx + ppx);
        Vy = 0.5f*(pry - ppy);
      }
      float xmr, xmi;
      if (c==0){ xmr=xh0[j].x; xmi=xh0[j].y; }
      else { xmr=Xs[(jj*17+c)*2]; xmi=Xs[(jj*17+c)*2+1]; }
      float zr = a*xmr + Vx;
      float zi = a*xmi + Vy;
      float wf = (side && c!=0)? 2.f : 1.f;
      float* dst = (side? Zk : Zq) + ((size_t)(t*16+h))*306 + m*2;
      dst[0]=wf*zr; dst[1]=wf*zi;
    }
    int b=t>>5, s=t&31;
    float vw=vsw[h], vb=vsb[h], pw=psw[h];
    size_t obase = ((size_t)(b*16+h)*32 + s)*1088;
    for (int e=threadIdx.x;e<544;e+=256){
      int j=e/17, c=e%17;
      float xr=Xs[e*2], xi=Xs[e*2+1];
      float wvr=0.f,wvi=0.f;
      if (c<=8 && (j<8||j>=24)){
        int jw=(j<8)? j : (j-16);
        const float* wv = value_w + ((size_t)(h*16+jw)*9 + c)*2;
        wvr=wv[0]; wvi=wv[1];
      }
      float Mr=xr*wvr-xi*wvi, Mi=xr*wvi+xi*wvr;
      float Mhr=Mr, Mhi=Mi;
      if (c==0){
        float Pr2=0.f,Pi2=0.f;
        int jp2=(j==0)?0:((j==16)?-1:32-j);
        if (jp2>=0 && (jp2<8||jp2>=24)){
          int jw2=(jp2<8)? jp2 : (jp2-16);
          const float* wv2=value_w+((size_t)(h*16+jw2)*9)*2;
          float pxr=Xs[(jp2*17)*2], pxi=Xs[(jp2*17)*2+1];
          Pr2=pxr*wv2[0]-pxi*wv2[1];
          Pi2=pxr*wv2[1]+pxi*wv2[0];
        }
        Mhr=0.5f*(Mr+Pr2); Mhi=0.5f*(Mi-Pi2);
      }
      float Yr=vw*xr+Mhr+((e==0)? vb:0.f);
      float Yi=vw*xi+Mhi;
      const float* pc=proj_w+((size_t)(h*32+j)*17+c)*2;
      float pr=pc[0], pi=pc[1];
      float* o=Yw+obase+e*2;
      o[0]=pr*Yr-pi*Yi+pw*Mr;
      o[1]=pr*Yi+pi*Yr+pw*Mi;
    }
  } else {
    int u=bx-2048;
    int b=u>>8, rem=u&255, t=rem>>3, sg=rem&7;
    float2* xt=(float2*)sh;
    const float2* src = (const float2*)(X64h + ((size_t)(b*32+t))*4224);
    for (int m=threadIdx.x;m<2112;m+=256){
      int r=m/33, c=m%33;
      bool excl = (c<=8) && (r<=8 || r>=56);
      float w = excl? 0.f : ((c==0||c==32)? 1.f : 2.f);
      float2 v = src[m];
      xt[m]=make_float2(v.x*w, v.y*w);
    }
    __syncthreads();
    float acc[4]={0.f,0.f,0.f,0.f};
    const float2* s0=(const float2*)(X64h + ((size_t)(b*32+sg*4))*4224);
    for (int m=threadIdx.x;m<2112;m+=256){
      float2 a2=xt[m];
      #pragma unroll
      for (int j=0;j<4;j++){
        float2 b2=s0[(size_t)j*2112+m];
        acc[j]+=a2.x*b2.x+a2.y*b2.y;
      }
    }
    for (int j=0;j<4;j++){
      float r=block_reduce1(acc[j]);
      if (threadIdx.x==0) Ue[((size_t)(b*32+t))*32 + sg*4+j]=r;
    }
  }
}

// ---- scores + fused softmax, t-split grid (4,16,2) -------------------------
__global__ __launch_bounds__(256) void k_scores2(const float* __restrict__ Zq, const float* __restrict__ Zk,
                          const float* __restrict__ Ue,
                          const float* __restrict__ qsw, const float* __restrict__ qsb,
                          const float* __restrict__ ksw, const float* __restrict__ ksb,
                          float* __restrict__ P){
  int b=blockIdx.x, h=blockIdx.y, tz=blockIdx.z;
  __shared__ float2 zq[16][154];
  __shared__ float2 zk[16][154];
  __shared__ float Pl[16][33];
  for (int i=threadIdx.x;i<16*153;i+=256){
    int t=i/153, m=i%153;
    zq[t][m]=((const float2*)(Zq + ((size_t)((b*32+tz*16+t)*16+h))*306))[m];
  }
  float aq=qsw[h], ak=ksw[h], bq=qsb[h], bk=ksb[h];
  float aqak=aq*ak;
  int tl=threadIdx.x>>4, sl=threadIdx.x&15;
  for (int ch=0; ch<2; ch++){
    __syncthreads();
    for (int i=threadIdx.x;i<16*153;i+=256){
      int s=i/153, m=i%153;
      zk[s][m]=((const float2*)(Zk + ((size_t)((b*32+ch*16+s)*16+h))*306))[m];
    }
    __syncthreads();
    float acc=0.f;
    for (int m=0;m<153;m++){
      float2 a2=zq[tl][m], c2=zk[sl][m];
      acc += a2.x*c2.x + a2.y*c2.y;
    }
    int s=ch*16+sl;
    float G = aqak*Ue[((size_t)(b*32+tz*16+tl))*32+s] + acc;
    Pl[tl][s] = 64.f*(G + bk*zq[tl][0].x + bq*zk[sl][0].x + bq*bk);
  }
  __syncthreads();
  if (threadIdx.x<16){
    int tt=threadIdx.x;
    float mx=-INFINITY;
    for (int s=0;s<32;s++) mx=fmaxf(mx,Pl[tt][s]);
    float e[32]; float sum=0.f;
    for (int s=0;s<32;s++){ e[s]=expf(Pl[tt][s]-mx); sum+=e[s]; }
    float inv=1.f/sum;
    size_t base=((size_t)(b*16+h)*32+tz*16+tt)*32;
    for (int s=0;s<32;s++) P[base+s]=e[s]*inv;
  }
}

// ---- merged SfC2 + skipmix (both consume P, independent) -------------------
__global__ __launch_bounds__(256) void k_SfSk(const float* __restrict__ x, const float* __restrict__ P,
        const float* __restrict__ Yw,
        const float* __restrict__ pw, const float* __restrict__ vw,
        const float* __restrict__ pstat0, const float* __restrict__ n1g, const float* __restrict__ n1b,
        float* __restrict__ Sfp, float* __restrict__ sk){
  __shared__ float sh[4096];
  int bx=blockIdx.x;
  if (bx<272){
    int b=bx/68, rem=bx%68, ec=rem/4, g=rem%4;
    int e0=ec*64, hs0=g*128;
    float (*Pl)[32] = (float(*)[32])sh;
    for (int i=threadIdx.x;i<128*32;i+=256){
      int hsl=i>>5, t=i&31;
      int hs=hs0+hsl, h=hs>>5, s=hs&31;
      Pl[hsl][t]=P[(((size_t)(b*16+h)*32)+t)*32+s];
    }
    __syncthreads();
    int el=threadIdx.x&63, tg=threadIdx.x>>6;
    float acc[8];
    #pragma unroll
    for (int j=0;j<8;j++) acc[j]=0.f;
    const float* Yb = Yw + ((size_t)b*512 + hs0)*1088 + e0 + el;
    #pragma unroll 4
    for (int hsl=0;hsl<128;hsl++){
      float y = Yb[(size_t)hsl*1088];
      #pragma unroll
      for (int j=0;j<8;j++) acc[j] += Pl[hsl][tg*8+j]*y;
    }
    #pragma unroll
    for (int j=0;j<8;j++){
      int t=tg*8+j;
      Sfp[((size_t)(b*32+t)*4+g)*1088 + e0 + el] = acc[j];
    }
  } else {
    int u=bx-272;
    int b=u>>6, rem=u&63, ch=rem>>1, tt=rem&1;
    int pxb=ch*512;
    float* Rs = sh;
    float* cbs = sh+512;
    float* as2 = sh+528;
    float* b0s = sh+560;
    if (threadIdx.x<32){
      float a,b0; affine_from(pstat0, n1g[0], n1b[0], b*32+threadIdx.x, a, b0);
      as2[threadIdx.x]=a; b0s[threadIdx.x]=b0;
    }
    __syncthreads();
    for (int rr=threadIdx.x; rr<512; rr+=256){
      int tl=rr>>5, s=rr&31;
      int t=tt*16+tl;
      float acc=0.f;
      for (int h=0;h<16;h++)
        acc += pw[h]*vw[h]*P[(((size_t)(b*16+h)*32)+t)*32+s];
      Rs[tl*32+s]=acc*as2[s];
      float cb=acc*b0s[s];
      for (int o=16;o>0;o>>=1) cb+=__shfl_down(cb,o,32);
      if (s==0) cbs[tl]=cb;
    }
    __syncthreads();
    float a0[16], a1[16];
    #pragma unroll
    for (int t=0;t<16;t++){ a0[t]=0.f; a1[t]=0.f; }
    for (int s=0;s<32;s++){
      const float* xp = x + ((size_t)(b*32+s))*NPIX + pxb;
      float v0=xp[threadIdx.x], v1=xp[threadIdx.x+256];
      #pragma unroll
      for (int t=0;t<16;t++){ float r=Rs[t*32+s]; a0[t]+=r*v0; a1[t]+=r*v1; }
    }
    #pragma unroll
    for (int t=0;t<16;t++){
      int gt=tt*16+t;
      float cb=cbs[t];
      float* op = sk + ((size_t)(b*32+gt))*NPIX + pxb;
      op[threadIdx.x]=a0[t]+cb; op[threadIdx.x+256]=a1[t]+cb;
    }
  }
}

// ======================= standalone tail kernels (fallback) =================
__global__ __launch_bounds__(256) void k_field0(const float* __restrict__ Sfp,
        const float* __restrict__ sk, const float* __restrict__ x,
        const float* __restrict__ psw, const float* __restrict__ vsb, const float* __restrict__ psb,
        float* __restrict__ zf, float* __restrict__ pstatA){
  int bt = blockIdx.x, slab = blockIdx.y;
  __shared__ float Ss[1088];
  __shared__ float T[8*17*2];
  __shared__ float tw[128][2];
  for (int i=threadIdx.x;i<1088;i+=256){
    const float* sp4 = Sfp + (size_t)bt*4352 + i;
    Ss[i] = sp4[0]+sp4[1088]+sp4[2176]+sp4[3264];
  }
  for (int p=threadIdx.x;p<128;p+=256){ float sn,cs; sincosf((2.f*PI_F/128.f)*(float)p,&sn,&cs); tw[p][0]=cs; tw[p][1]=sn; }
  __syncthreads();
  int h0 = slab*8;
  for (int e=threadIdx.x;e<136;e+=256){
    int hl=e/17, c=e%17; int h=h0+hl;
    float re=0.f, im=0.f;
    for (int j=0;j<32;j++){
      int r=(j<16)? j : (j+96);
      int p=(r*h)&127;
      float cs=tw[p][0], sn=tw[p][1];
      float ar=Ss[(j*17+c)*2], ai=Ss[(j*17+c)*2+1];
      re += ar*cs - ai*sn;
      im += ar*sn + ai*cs;
    }
    T[e*2]=re; T[e*2+1]=im;
  }
  __syncthreads();
  size_t base = (size_t)bt*NPIX + h0*128;
  float Cb = psb[0];
  for (int hh=0;hh<16;hh++) Cb += psw[hh]*vsb[hh];
  float sum=0.f, sq=0.f;
  for (int pos=threadIdx.x;pos<1024;pos+=256){
    int hl=pos>>7, w=pos&127;
    const float* Th=T+hl*17*2;
    float br=tw[w][0], bi=tw[w][1];
    float rr=br, ri=bi;
    float v=Th[0];
    for (int c=1;c<17;c++){
      v += 2.f*(Th[c*2]*rr - Th[c*2+1]*ri);
      float nr=rr*br-ri*bi; ri=rr*bi+ri*br; rr=nr;
    }
    float val = v + sk[base+pos] + x[base+pos] + Cb;
    zf[base+pos]=val; sum+=val; sq+=val*val;
  }
  block_reduce2(sum,sq);
  if (threadIdx.x==0){ float* o=pstatA+((size_t)bt*16+slab)*2; o[0]=sum; o[1]=sq; }
}

__global__ __launch_bounds__(256) void k_specm0(const float* __restrict__ P,
    const float* __restrict__ pw, const float* __restrict__ vw,
    const float* __restrict__ Sfp, const float* __restrict__ X64,
    const float* __restrict__ pstat0, const float* __restrict__ pstatA,
    const float* __restrict__ n1g, const float* __restrict__ n1b,
    const float* __restrict__ ag, const float* __restrict__ n2g, const float* __restrict__ n2b,
    const float* __restrict__ psw, const float* __restrict__ vsb, const float* __restrict__ psb,
    float* __restrict__ sp){
  int bt=blockIdx.x, ec=blockIdx.y; int b=bt>>5, t=bt&31;
  __shared__ float Rs[32];
  __shared__ float Sfl[1088];
  if (threadIdx.x<32){
    int s=threadIdx.x; float acc=0.f;
    for (int h=0;h<16;h++)
      acc += pw[h]*vw[h]*P[(((size_t)(b*16+h)*32)+t)*32+s];
    Rs[s]=acc;
  }
  for (int i=threadIdx.x;i<1088;i+=256){
    const float* sp4 = Sfp + (size_t)bt*4352 + i;
    Sfl[i]=sp4[0]+sp4[1088]+sp4[2176]+sp4[3264];
  }
  __syncthreads();
  float a_t,b0_t; affine_from(pstat0,n1g[0],n1b[0],bt,a_t,b0_t);
  float muZ,aA,a0; scalA_from(pstatA,ag[0],n2g[0],bt,muZ,aA,a0);
  float Cb=psb[0];
  for (int h=0;h<16;h++) Cb+=psw[h]*vsb[h];
  float inva=1.f/a_t;
  int e1=ec*272, e2=e1+272;
  for (int e=e1+threadIdx.x;e<e2;e+=256){
    int j=e/17, c=e%17;
    float sr=Sfl[e*2], si=Sfl[e*2+1];
    if (c==0){
      if (j==0){ si=0.f; }
      else if (j==16){ sr*=0.5f; si*=0.5f; }
      else { int jp=32-j; sr=0.5f*(sr+Sfl[jp*34]); si=0.5f*(si-Sfl[jp*34+1]); }
    }
    int i2=(j<16)? j : (j+32);
    float re=0.f, im=0.f;
    const float* xb = X64 + ((size_t)(b*32)*(64*33) + i2*33 + c)*2;
    for (int s=0;s<32;s++){
      const float* xp = xb + (size_t)s*(64*33)*2;
      float r=Rs[s];
      re += r*xp[0]; im += r*xp[1];
    }
    const float* xt = X64 + ((size_t)bt*(64*33) + i2*33 + c)*2;
    re += inva*xt[0]; im += inva*xt[1];
    float zr=sr+re, zi=si+im;
    if (e==0) zr += Cb - b0_t*inva;
    float mr=a0*zr, mi=a0*zi;
    if (e==0) mr += n2b[0] - muZ*a0;
    sp[((size_t)bt*544+e)*2]=mr; sp[((size_t)bt*544+e)*2+1]=mi;
  }
}

__global__ __launch_bounds__(256) void k_field1(const float* __restrict__ sp, const float* __restrict__ wm,
        float* __restrict__ fd1, float* __restrict__ pstatB){
  int bt = blockIdx.x, slab = blockIdx.y;
  __shared__ float Ss[1088];
  __shared__ float T[8*17*2];
  __shared__ float tw[128][2];
  for (int e=threadIdx.x;e<544;e+=256){
    float xr=sp[((size_t)bt*544+e)*2], xi=sp[((size_t)bt*544+e)*2+1];
    float wr=wm[e*2], wi=wm[e*2+1];
    Ss[e*2]=xr*wr-xi*wi; Ss[e*2+1]=xr*wi+xi*wr;
  }
  for (int p=threadIdx.x;p<128;p+=256){ float sn,cs; sincosf((2.f*PI_F/128.f)*(float)p,&sn,&cs); tw[p][0]=cs; tw[p][1]=sn; }
  __syncthreads();
  int h0 = slab*8;
  for (int e=threadIdx.x;e<136;e+=256){
    int hl=e/17, c=e%17; int h=h0+hl;
    float re=0.f, im=0.f;
    for (int j=0;j<32;j++){
      int r=(j<16)? j : (j+96);
      int p=(r*h)&127;
      float cs=tw[p][0], sn=tw[p][1];
      float ar=Ss[(j*17+c)*2], ai=Ss[(j*17+c)*2+1];
      re += ar*cs - ai*sn;
      im += ar*sn + ai*cs;
    }
    T[e*2]=re; T[e*2+1]=im;
  }
  __syncthreads();
  size_t base = (size_t)bt*NPIX + h0*128;
  float sum=0.f, sq=0.f;
  for (int pos=threadIdx.x;pos<1024;pos+=256){
    int hl=pos>>7, w=pos&127;
    const float* Th=T+hl*17*2;
    float br=tw[w][0], bi=tw[w][1];
    float rr=br, ri=bi;
    float v=Th[0];
    for (int c=1;c<17;c++){
      v += 2.f*(Th[c*2]*rr - Th[c*2+1]*ri);
      float nr=rr*br-ri*bi; ri=rr*bi+ri*br; rr=nr;
    }
    fd1[base+pos]=v; sum+=v; sq+=v*v;
  }
  block_reduce2(sum,sq);
  if (threadIdx.x==0){ float* o=pstatB+((size_t)bt*16+slab)*2; o[0]=sum; o[1]=sq; }
}

__global__ __launch_bounds__(256) void k_colA1(const float* __restrict__ f1, const float* __restrict__ z,
        const float* __restrict__ pstatA, const float* __restrict__ pstatB,
        const float* __restrict__ ag, const float* __restrict__ n2g, const float* __restrict__ mng1,
        const float* __restrict__ n2b,
        const float* __restrict__ mnb1, const float* __restrict__ msw1, const float* __restrict__ msb1,
        float* __restrict__ A){
  __shared__ float rows[16*128];
  __shared__ float tw[128][2];
  int grow = blockIdx.x*16;
  int t = grow>>7;
  float muZ,aA,a0;
  scalA_from(pstatA, ag[0], n2g[0], t, muZ, aA, a0);
  float b2 = n2b[0];
  float mu1,c1;
  scalB_from(pstatB, mng1[0], t, mu1, c1);
  float nb=mnb1[0], sw=msw1[0], sb=msb1[0];
  for (int i=threadIdx.x;i<2048;i+=256){
    size_t gi=(size_t)grow*128+i;
    float m0v=(z[gi]-muZ)*a0+b2;
    float y=(f1[gi]-mu1)*c1+nb + m0v*sw + sb;
    rows[i]=gelu_f(y);
  }
  for (int p=threadIdx.x;p<128;p+=256){ float sn,cs; sincosf(-(2.f*PI_F/128.f)*(float)p,&sn,&cs); tw[p][0]=cs; tw[p][1]=sn; }
  __syncthreads();
  for (int e=threadIdx.x;e<16*17;e+=256){
    int r=e/17, c=e%17;
    const float* rp=rows+r*128;
    float re=0.f, im=0.f;
    for (int w=0;w<128;w++){
      int p=(c*w)&127;
      float v=rp[w];
      re+=v*tw[p][0]; im+=v*tw[p][1];
    }
    float* o=A+((size_t)(grow+r)*17+c)*2; o[0]=re; o[1]=im;
  }
}

__global__ __launch_bounds__(256) void k_rowfft32(const float* __restrict__ A, float* __restrict__ spec){
  int s=blockIdx.x, cg2=blockIdx.y;
  int c0 = (cg2==0)? 0 : (1+cg2*4);
  int nc = (cg2==0)? 5 : 4;
  __shared__ float a[128*5*2];
  __shared__ float tw[128][2];
  for (int i=threadIdx.x;i<128*nc*2;i+=256){
    int r=i/(2*nc), q=i%(2*nc);
    a[(r*5+(q>>1))*2+(q&1)] = A[((size_t)(s*128+r)*17 + c0)*2 + q];
  }
  for (int p=threadIdx.x;p<128;p+=256){ float sn,cs; sincosf(-(2.f*PI_F/128.f)*(float)p,&sn,&cs); tw[p][0]=cs; tw[p][1]=sn; }
  __syncthreads();
  const float sc=1.f/16384.f;
  for (int e=threadIdx.x;e<32*nc;e+=256){
    int j=e/nc, cl=e%nc;
    int r=(j<16)? j : (j+96);
    float re=0.f,im=0.f;
    for (int h=0;h<128;h++){
      int p=(r*h)&127;
      float cs=tw[p][0], sn=tw[p][1];
      float ar=a[(h*5+cl)*2], ai=a[(h*5+cl)*2+1];
      re += ar*cs - ai*sn;
      im += ar*sn + ai*cs;
    }
    float* o=spec+((size_t)s*544 + j*17 + c0+cl)*2;
    o[0]=re*sc; o[1]=im*sc;
  }
}

__global__ __launch_bounds__(256) void k_field2(const float* __restrict__ sp2, const float* __restrict__ wm,
        const float* __restrict__ f1, const float* __restrict__ z,
        const float* __restrict__ pstatA, const float* __restrict__ pstatB,
        const float* __restrict__ ag, const float* __restrict__ n2g, const float* __restrict__ mng1,
        const float* __restrict__ n2b, const float* __restrict__ mnb1,
        const float* __restrict__ msw1, const float* __restrict__ msb1,
        float* __restrict__ fd2, float* __restrict__ pstatC){
  int bt = blockIdx.x, slab = blockIdx.y;
  __shared__ float Ss[1088];
  __shared__ float T[8*17*2];
  __shared__ float tw[128][2];
  for (int e=threadIdx.x;e<544;e+=256){
    float xr=sp2[((size_t)bt*544+e)*2], xi=sp2[((size_t)bt*544+e)*2+1];
    float wr=wm[e*2], wi=wm[e*2+1];
    Ss[e*2]=xr*wr-xi*wi; Ss[e*2+1]=xr*wi+xi*wr;
  }
  for (int p=threadIdx.x;p<128;p+=256){ float sn,cs; sincosf((2.f*PI_F/128.f)*(float)p,&sn,&cs); tw[p][0]=cs; tw[p][1]=sn; }
  __syncthreads();
  int h0 = slab*8;
  for (int e=threadIdx.x;e<136;e+=256){
    int hl=e/17, c=e%17; int h=h0+hl;
    float re=0.f, im=0.f;
    for (int j=0;j<32;j++){
      int r=(j<16)? j : (j+96);
      int p=(r*h)&127;
      float cs=tw[p][0], sn=tw[p][1];
      float ar=Ss[(j*17+c)*2], ai=Ss[(j*17+c)*2+1];
      re += ar*cs - ai*sn;
      im += ar*sn + ai*cs;
    }
    T[e*2]=re; T[e*2+1]=im;
  }
  __syncthreads();
  size_t base = (size_t)bt*NPIX + h0*128;
  float muZ,aA,a0,mu1,c1;
  scalA_from(pstatA, ag[0], n2g[0], bt, muZ, aA, a0);
  scalB_from(pstatB, mng1[0], bt, mu1, c1);
  float b2=n2b[0], nb1=mnb1[0], sw1=msw1[0], sb1=msb1[0];
  float s_f=0.f,s_fsq=0.f,s_m=0.f,s_msq=0.f,s_x=0.f;
  for (int pos=threadIdx.x;pos<1024;pos+=256){
    int hl=pos>>7, w=pos&127;
    const float* Th=T+hl*17*2;
    float br=tw[w][0], bi=tw[w][1];
    float rr=br, ri=bi;
    float v=Th[0];
    for (int c=1;c<17;c++){
      v += 2.f*(Th[c*2]*rr - Th[c*2+1]*ri);
      float nr=rr*br-ri*bi; ri=rr*bi+ri*br; rr=nr;
    }
    size_t gi=base+pos;
    float m0v=(z[gi]-muZ)*a0+b2;
    float y=(f1[gi]-mu1)*c1+nb1 + m0v*sw1 + sb1;
    float m1v=gelu_f(y);
    fd2[gi]=v;
    s_f+=v; s_fsq+=v*v; s_m+=m1v; s_msq+=m1v*m1v; s_x+=v*m1v;
  }
  block_reduce2(s_f,s_fsq);
  block_reduce2(s_m,s_msq);
  s_x = block_reduce1(s_x);
  if (threadIdx.x==0){
    float* o=pstatC+((size_t)bt*16+slab)*5;
    o[0]=s_f; o[1]=s_fsq; o[2]=s_m; o[3]=s_msq; o[4]=s_x;
  }
}

__global__ __launch_bounds__(256) void k_final2(const float* __restrict__ z, const float* __restrict__ f1,
        const float* __restrict__ f2,
        const float* __restrict__ pstatA, const float* __restrict__ pstatB, const float* __restrict__ pstatC,
        const float* __restrict__ ag, const float* __restrict__ n2g, const float* __restrict__ mng1,
        const float* __restrict__ mng2, const float* __restrict__ outg,
        const float* __restrict__ ab, const float* __restrict__ n2b,
        const float* __restrict__ mnb1, const float* __restrict__ msw1, const float* __restrict__ msb1,
        const float* __restrict__ mnb2, const float* __restrict__ msw2, const float* __restrict__ msb2,
        const float* __restrict__ outb, float* __restrict__ out){
  int bt=blockIdx.x, slab=blockIdx.y;
  float muZ,aA,a0,mu1,c1,mu2f,c2,mu3,c3;
  scalA_from(pstatA, ag[0], n2g[0], bt, muZ, aA, a0);
  scalB_from(pstatB, mng1[0], bt, mu1, c1);
  float sw2=msw2[0], K=mnb2[0]+msb2[0];
  scalC_from(pstatC, mng2[0], K, sw2, outg[0], bt, mu2f, c2, mu3, c3);
  float b1=ab[0], b2=n2b[0], nb1=mnb1[0], sw1=msw1[0], sb1=msb1[0];
  float nb2=mnb2[0], sb2=msb2[0], bo=outb[0];
  size_t base=(size_t)bt*NPIX + (size_t)slab*1024;
  for (int i=threadIdx.x;i<1024;i+=256){
    size_t gi=base+i;
    float zv=z[gi];
    float m0v=(zv-muZ)*a0+b2;
    float a2v=(zv-muZ)*aA+b1;
    float y=(f1[gi]-mu1)*c1+nb1 + m0v*sw1 + sb1;
    float m1v=gelu_f(y);
    float m2v=(f2[gi]-mu2f)*c2+nb2 + m1v*sw2 + sb2;
    out[gi]=(m2v-mu3)*c3+bo+a2v;
  }
}

// ======== fused cooperative tail (conservative config) ======================
struct TailArgs {
  const float *Sfp, *sk, *x, *P, *X64, *pstat0;
  float *pstatA, *pstatB, *pstatC, *sp, *sp2, *A, *zf, *fd1, *fd2, *out;
  const float *n1g,*n1b,*ag,*n2g,*n2b,*mng1,*mnb1,*msw1,*msb1,*mw1,*mw2;
  const float *mng2,*mnb2,*msw2,*msb2,*outg,*outb,*ab,*psw,*vsb,*psb,*pw,*vw;
};

#define TAIL_GRID 512

__global__ __launch_bounds__(256,2) void k_tail(TailArgs Aa){
  cg::grid_group gg = cg::this_grid();
  __shared__ float sh[2304];

  // ===== stage 0: field0 (2048 units) =====
  {
    float* tw = sh+1360;
    for (int p=threadIdx.x;p<128;p+=256){ float sn,cs; sincosf((2.f*PI_F/128.f)*(float)p,&sn,&cs); tw[p*2]=cs; tw[p*2+1]=sn; }
    float Cb = Aa.psb[0];
    for (int hh=0;hh<16;hh++) Cb += Aa.psw[hh]*Aa.vsb[hh];
    for (int u=blockIdx.x; u<2048; u+=TAIL_GRID){
      int bt=u>>4, slab=u&15;
      __syncthreads();
      float* Ss=sh; float* T=sh+1088;
      for (int i=threadIdx.x;i<1088;i+=256){
        const float* sp4 = Aa.Sfp + (size_t)bt*4352 + i;
        Ss[i] = sp4[0]+sp4[1088]+sp4[2176]+sp4[3264];
      }
      __syncthreads();
      int h0 = slab*8;
      for (int e=threadIdx.x;e<136;e+=256){
        int hl=e/17, c=e%17; int h=h0+hl;
        float re=0.f, im=0.f;
        for (int j=0;j<32;j++){
          int r=(j<16)? j : (j+96);
          int p=(r*h)&127;
          float cs=tw[p*2], sn=tw[p*2+1];
          float ar=Ss[(j*17+c)*2], ai=Ss[(j*17+c)*2+1];
          re += ar*cs - ai*sn;
          im += ar*sn + ai*cs;
        }
        T[e*2]=re; T[e*2+1]=im;
      }
      __syncthreads();
      size_t base = (size_t)bt*NPIX + h0*128;
      float sum=0.f, sq=0.f;
      for (int pos=threadIdx.x;pos<1024;pos+=256){
        int hl=pos>>7, w=pos&127;
        const float* Th=T+hl*17*2;
        float br=tw[w*2], bi=tw[w*2+1];
        float rr=br, ri=bi;
        float v=Th[0];
        for (int c=1;c<17;c++){
          v += 2.f*(Th[c*2]*rr - Th[c*2+1]*ri);
          float nr=rr*br-ri*bi; ri=rr*bi+ri*br; rr=nr;
        }
        float val = v + Aa.sk[base+pos] + Aa.x[base+pos] + Cb;
        Aa.zf[base+pos]=val; sum+=val; sq+=val*val;
      }
      block_reduce2(sum,sq);
      if (threadIdx.x==0){ float* o=Aa.pstatA+((size_t)bt*16+slab)*2; o[0]=sum; o[1]=sq; }
    }
  }
  gg.sync();

  // ===== stage 1: specm0 (256 units) =====
  {
    for (int u=blockIdx.x; u<256; u+=TAIL_GRID){
      int bt=u>>1, ec=u&1; int b=bt>>5, t=bt&31;
      __syncthreads();
      float* Sfl=sh; float* Rs=sh+1088;
      if (threadIdx.x<32){
        int s=threadIdx.x; float acc=0.f;
        for (int h=0;h<16;h++)
          acc += Aa.pw[h]*Aa.vw[h]*Aa.P[(((size_t)(b*16+h)*32)+t)*32+s];
        Rs[s]=acc;
      }
      for (int i=threadIdx.x;i<1088;i+=256){
        const float* sp4 = Aa.Sfp + (size_t)bt*4352 + i;
        Sfl[i]=sp4[0]+sp4[1088]+sp4[2176]+sp4[3264];
      }
      __syncthreads();
      float a_t,b0_t; affine_from(Aa.pstat0,Aa.n1g[0],Aa.n1b[0],bt,a_t,b0_t);
      float muZ,aA,a0; scalA_from(Aa.pstatA,Aa.ag[0],Aa.n2g[0],bt,muZ,aA,a0);
      float Cb=Aa.psb[0];
      for (int h=0;h<16;h++) Cb+=Aa.psw[h]*Aa.vsb[h];
      float inva=1.f/a_t;
      int e1=ec*272, e2=e1+272;
      for (int e=e1+threadIdx.x;e<e2;e+=256){
        int j=e/17, c=e%17;
        float sr=Sfl[e*2], si=Sfl[e*2+1];
        if (c==0){
          if (j==0){ si=0.f; }
          else if (j==16){ sr*=0.5f; si*=0.5f; }
          else { int jp=32-j; sr=0.5f*(sr+Sfl[jp*34]); si=0.5f*(si-Sfl[jp*34+1]); }
        }
        int i2=(j<16)? j : (j+32);
        float re=0.f, im=0.f;
        const float* xb = Aa.X64 + ((size_t)(b*32)*(64*33) + i2*33 + c)*2;
        for (int s=0;s<32;s++){
          const float* xp = xb + (size_t)s*(64*33)*2;
          float r=Rs[s];
          re += r*xp[0]; im += r*xp[1];
        }
        const float* xt = Aa.X64 + ((size_t)bt*(64*33) + i2*33 + c)*2;
        re += inva*xt[0]; im += inva*xt[1];
        float zr=sr+re, zi=si+im;
        if (e==0) zr += Cb - b0_t*inva;
        float mr=a0*zr, mi=a0*zi;
        if (e==0) mr += Aa.n2b[0] - muZ*a0;
        Aa.sp[((size_t)bt*544+e)*2]=mr; Aa.sp[((size_t)bt*544+e)*2+1]=mi;
      }
    }
  }
  gg.sync();

  // ===== stage 2: field1 (2048 units) =====
  {
    float* tw = sh+1360;
    for (int p=threadIdx.x;p<128;p+=256){ float sn,cs; sincosf((2.f*PI_F/128.f)*(float)p,&sn,&cs); tw[p*2]=cs; tw[p*2+1]=sn; }
    for (int u=blockIdx.x; u<2048; u+=TAIL_GRID){
      int bt=u>>4, slab=u&15;
      __syncthreads();
      float* Ss=sh; float* T=sh+1088;
      for (int e=threadIdx.x;e<544;e+=256){
        float xr=Aa.sp[((size_t)bt*544+e)*2], xi=Aa.sp[((size_t)bt*544+e)*2+1];
        float wr=Aa.mw1[e*2], wi=Aa.mw1[e*2+1];
        Ss[e*2]=xr*wr-xi*wi; Ss[e*2+1]=xr*wi+xi*wr;
      }
      __syncthreads();
      int h0 = slab*8;
      for (int e=threadIdx.x;e<136;e+=256){
        int hl=e/17, c=e%17; int h=h0+hl;
        float re=0.f, im=0.f;
        for (int j=0;j<32;j++){
          int r=(j<16)? j : (j+96);
          int p=(r*h)&127;
          float cs=tw[p*2], sn=tw[p*2+1];
          float ar=Ss[(j*17+c)*2], ai=Ss[(j*17+c)*2+1];
          re += ar*cs - ai*sn;
          im += ar*sn + ai*cs;
        }
        T[e*2]=re; T[e*2+1]=im;
      }
      __syncthreads();
      size_t base = (size_t)bt*NPIX + h0*128;
      float sum=0.f, sq=0.f;
      for (int pos=threadIdx.x;pos<1024;pos+=256){
        int hl=pos>>7, w=pos&127;
        const float* Th=T+hl*17*2;
        float br=tw[w*2], bi=tw[w*2+1];
        float rr=br, ri=bi;
        float v=Th[0];
        for (int c=1;c<17;c++){
          v += 2.f*(Th[c*2]*rr - Th[c*2+1]*ri);
          float nr=rr*br-ri*bi; ri=rr*bi+ri*br; rr=nr;
        }
        Aa.fd1[base+pos]=v; sum+=v; sq+=v*v;
      }
      block_reduce2(sum,sq);
      if (threadIdx.x==0){ float* o=Aa.pstatB+((size_t)bt*16+slab)*2; o[0]=sum; o[1]=sq; }
    }
  }
  gg.sync();

  // ===== stage 3: colA1 (1024 units) =====
  {
    float* tw = sh+2048;
    for (int p=threadIdx.x;p<128;p+=256){ float sn,cs; sincosf(-(2.f*PI_F/128.f)*(float)p,&sn,&cs); tw[p*2]=cs; tw[p*2+1]=sn; }
    for (int u=blockIdx.x; u<1024; u+=TAIL_GRID){
      int grow=u*16; int t=grow>>7;
      __syncthreads();
      float* rows=sh;
      float muZ,aA,a0;
      scalA_from(Aa.pstatA, Aa.ag[0], Aa.n2g[0], t, muZ, aA, a0);
      float b2 = Aa.n2b[0];
      float mu1,c1;
      scalB_from(Aa.pstatB, Aa.mng1[0], t, mu1, c1);
      float nb=Aa.mnb1[0], sw=Aa.msw1[0], sb=Aa.msb1[0];
      for (int i=threadIdx.x;i<2048;i+=256){
        size_t gi=(size_t)grow*128+i;
        float m0v=(Aa.zf[gi]-muZ)*a0+b2;
        float y=(Aa.fd1[gi]-mu1)*c1+nb + m0v*sw + sb;
        rows[i]=gelu_f(y);
      }
      __syncthreads();
      for (int e=threadIdx.x;e<16*17;e+=256){
        int r=e/17, c=e%17;
        const float* rp=rows+r*128;
        float re=0.f, im=0.f;
        for (int w=0;w<128;w++){
          int p=(c*w)&127;
          float v=rp[w];
          re+=v*tw[p*2]; im+=v*tw[p*2+1];
        }
        float* o=Aa.A+((size_t)(grow+r)*17+c)*2; o[0]=re; o[1]=im;
      }
    }
  }
  gg.sync();

  // ===== stage 4: rowfft32 (512 units) =====
  {
    float* tw = sh+2048;
    for (int p=threadIdx.x;p<128;p+=256){ float sn,cs; sincosf(-(2.f*PI_F/128.f)*(float)p,&sn,&cs); tw[p*2]=cs; tw[p*2+1]=sn; }
    const float sc=1.f/16384.f;
    for (int u=blockIdx.x; u<512; u+=TAIL_GRID){
      int s=u>>2, cg2=u&3;
      int c0 = (cg2==0)? 0 : (1+cg2*4);
      int nc = (cg2==0)? 5 : 4;
      __syncthreads();
      float* a=sh;
      for (int i=threadIdx.x;i<128*nc*2;i+=256){
        int r=i/(2*nc), q=i%(2*nc);
        a[(r*5+(q>>1))*2+(q&1)] = Aa.A[((size_t)(s*128+r)*17 + c0)*2 + q];
      }
      __syncthreads();
      for (int e=threadIdx.x;e<32*nc;e+=256){
        int j=e/nc, cl=e%nc;
        int r=(j<16)? j : (j+96);
        float re=0.f,im=0.f;
        for (int h=0;h<128;h++){
          int p=(r*h)&127;
          float cs=tw[p*2], sn=tw[p*2+1];
          float ar=a[(h*5+cl)*2], ai=a[(h*5+cl)*2+1];
          re += ar*cs - ai*sn;
          im += ar*sn + ai*cs;
        }
        float* o=Aa.sp2+((size_t)s*544 + j*17 + c0+cl)*2;
        o[0]=re*sc; o[1]=im*sc;
      }
    }
  }
  gg.sync();

  // ===== stage 5: field2 (2048 units) =====
  {
    float* tw = sh+1360;
    for (int p=threadIdx.x;p<128;p+=256){ float sn,cs; sincosf((2.f*PI_F/128.f)*(float)p,&sn,&cs); tw[p*2]=cs; tw[p*2+1]=sn; }
    for (int u=blockIdx.x; u<2048; u+=TAIL_GRID){
      int bt=u>>4, slab=u&15;
      __syncthreads();
      float* Ss=sh; float* T=sh+1088;
      for (int e=threadIdx.x;e<544;e+=256){
        float xr=Aa.sp2[((size_t)bt*544+e)*2], xi=Aa.sp2[((size_t)bt*544+e)*2+1];
        float wr=Aa.mw2[e*2], wi=Aa.mw2[e*2+1];
        Ss[e*2]=xr*wr-xi*wi; Ss[e*2+1]=xr*wi+xi*wr;
      }
      __syncthreads();
      int h0 = slab*8;
      for (int e=threadIdx.x;e<136;e+=256){
        int hl=e/17, c=e%17; int h=h0+hl;
        float re=0.f, im=0.f;
        for (int j=0;j<32;j++){
          int r=(j<16)? j : (j+96);
          int p=(r*h)&127;
          float cs=tw[p*2], sn=tw[p*2+1];
          float ar=Ss[(j*17+c)*2], ai=Ss[(j*17+c)*2+1];
          re += ar*cs - ai*sn;
          im += ar*sn + ai*cs;
        }
        T[e*2]=re; T[e*2+1]=im;
      }
      __syncthreads();
      size_t base = (size_t)bt*NPIX + h0*128;
      float muZ,aA,a0,mu1,c1;
      scalA_from(Aa.pstatA, Aa.ag[0], Aa.n2g[0], bt, muZ, aA, a0);
      scalB_from(Aa.pstatB, Aa.mng1[0], bt, mu1, c1);
      float b2=Aa.n2b[0], nb1=Aa.mnb1[0], sw1=Aa.msw1[0], sb1=Aa.msb1[0];
      float s_f=0.f,s_fsq=0.f,s_m=0.f,s_msq=0.f,s_x=0.f;
      for (int pos=threadIdx.x;pos<1024;pos+=256){
        int hl=pos>>7, w=pos&127;
        const float* Th=T+hl*17*2;
        float br=tw[w*2], bi=tw[w*2+1];
        float rr=br, ri=bi;
        float v=Th[0];
        for (int c=1;c<17;c++){
          v += 2.f*(Th[c*2]*rr - Th[c*2+1]*ri);
          float nr=rr*br-ri*bi; ri=rr*bi+ri*br; rr=nr;
        }
        size_t gi=base+pos;
        float m0v=(Aa.zf[gi]-muZ)*a0+b2;
        float y=(Aa.fd1[gi]-mu1)*c1+nb1 + m0v*sw1 + sb1;
        float m1v=gelu_f(y);
        Aa.fd2[gi]=v;
        s_f+=v; s_fsq+=v*v; s_m+=m1v; s_msq+=m1v*m1v; s_x+=v*m1v;
      }
      block_reduce2(s_f,s_fsq);
      block_reduce2(s_m,s_msq);
      s_x = block_reduce1(s_x);
      if (threadIdx.x==0){
        float* o=Aa.pstatC+((size_t)bt*16+slab)*5;
        o[0]=s_f; o[1]=s_fsq; o[2]=s_m; o[3]=s_msq; o[4]=s_x;
      }
    }
  }
  gg.sync();

  // ===== stage 6: final2 (2048 units) =====
  {
    for (int u=blockIdx.x; u<2048; u+=TAIL_GRID){
      int bt=u>>4, slab=u&15;
      float muZ,aA,a0,mu1,c1,mu2f,c2,mu3,c3;
      scalA_from(Aa.pstatA, Aa.ag[0], Aa.n2g[0], bt, muZ, aA, a0);
      scalB_from(Aa.pstatB, Aa.mng1[0], bt, mu1, c1);
      float sw2=Aa.msw2[0], K=Aa.mnb2[0]+Aa.msb2[0];
      scalC_from(Aa.pstatC, Aa.mng2[0], K, sw2, Aa.outg[0], bt, mu2f, c2, mu3, c3);
      float b1=Aa.ab[0], b2=Aa.n2b[0], nb1=Aa.mnb1[0], sw1=Aa.msw1[0], sb1=Aa.msb1[0];
      float nb2=Aa.mnb2[0], sb2=Aa.msb2[0], bo=Aa.outb[0];
      size_t base=(size_t)bt*NPIX + (size_t)slab*1024;
      for (int i=threadIdx.x;i<1024;i+=256){
        size_t gi=base+i;
        float zv=Aa.zf[gi];
        float m0v=(zv-muZ)*a0+b2;
        float a2v=(zv-muZ)*aA+b1;
        float y=(Aa.fd1[gi]-mu1)*c1+nb1 + m0v*sw1 + sb1;
        float m1v=gelu_f(y);
        float m2v=(Aa.fd2[gi]-mu2f)*c2+nb2 + m1v*sw2 + sb2;
        Aa.out[gi]=(m2v-mu3)*c3+bo+a2v;
      }
    }
  }
}

extern "C" void kernel_launch(void* const* d_in, const int* in_sizes, int n_in,
                              void* d_out, int out_size, void* d_ws, size_t ws_size,
                              hipStream_t stream){
  const float* x        = (const float*)d_in[0];
  const float* key_w    = (const float*)d_in[1];
  const float* key_sw   = (const float*)d_in[2];
  const float* key_sb   = (const float*)d_in[3];
  const float* query_w  = (const float*)d_in[4];
  const float* query_sw = (const float*)d_in[5];
  const float* query_sb = (const float*)d_in[6];
  const float* value_w  = (const float*)d_in[7];
  const float* value_sw = (const float*)d_in[8];
  const float* value_sb = (const float*)d_in[9];
  const float* proj_w   = (const float*)d_in[10];
  const float* proj_sw  = (const float*)d_in[11];
  const float* proj_sb  = (const float*)d_in[12];
  const float* norm1_g  = (const float*)d_in[13];
  const float* norm1_b  = (const float*)d_in[14];
  const float* attn_g   = (const float*)d_in[15];
  const float* attn_b   = (const float*)d_in[16];
  const float* norm2_g  = (const float*)d_in[17];
  const float* norm2_b  = (const float*)d_in[18];
  const float* mw1      = (const float*)d_in[19];
  const float* msw1     = (const float*)d_in[20];
  const float* msb1     = (const float*)d_in[21];
  const float* mng1     = (const float*)d_in[22];
  const float* mnb1     = (const float*)d_in[23];
  const float* mw2      = (const float*)d_in[24];
  const float* msw2     = (const float*)d_in[25];
  const float* msb2     = (const float*)d_in[26];
  const float* mng2     = (const float*)d_in[27];
  const float* mnb2     = (const float*)d_in[28];
  const float* outg     = (const float*)d_in[29];
  const float* outb     = (const float*)d_in[30];
  float* out = (float*)d_out;
  float* ws  = (float*)d_ws;

  size_t off=0;
  float* A   = ws + off; off += (size_t)128*128*33*2;
  float* X64 = ws + off; off += (size_t)128*64*33*2;
  float* X64h= ws + off; off += (size_t)128*64*33*2;
  float* Zq  = ws + off; off += (size_t)128*16*306;
  float* Zk  = ws + off; off += (size_t)128*16*306;
  float* Ue  = ws + off; off += (size_t)4*32*32;
  float* P   = ws + off; off += (size_t)4*16*32*32;
  float* Yw  = ws + off; off += (size_t)2048*1088;
  float* Sfp = ws + off; off += (size_t)128*4*1088;
  float* sk  = ws + off; off += (size_t)128*16384;
  float* zf  = ws + off; off += (size_t)128*16384;
  float* fd1 = ws + off; off += (size_t)128*16384;
  float* fd2 = ws + off; off += (size_t)128*16384;
  float* sp  = ws + off; off += (size_t)128*544*2;
  float* sp2 = ws + off; off += (size_t)128*544*2;
  float* pstat0 = ws + off; off += (size_t)128*8*2;
  float* pstatA = ws + off; off += (size_t)128*16*2;
  float* pstatB = ws + off; off += (size_t)128*16*2;
  float* pstatC = ws + off; off += (size_t)128*16*5;

  k_stats0<<<dim3(128,8),256,0,stream>>>(x, pstat0);
  k_colfft33<<<1024,256,0,stream>>>(x, pstat0, norm1_g, norm1_b, A);
  k_rowfft64<<<dim3(128,3),256,0,stream>>>(A, X64, X64h);
  k_UeZYw<<<3072,256,0,stream>>>(X64, X64h, query_w, query_sw, key_w, key_sw,
      value_w, value_sw, value_sb, proj_w, proj_sw, Zq, Zk, Yw, Ue);
  k_scores2<<<dim3(4,16,2),256,0,stream>>>(Zq, Zk, Ue, query_sw, query_sb, key_sw, key_sb, P);
  k_SfSk<<<528,256,0,stream>>>(x, P, Yw, proj_sw, value_sw, pstat0, norm1_g, norm1_b, Sfp, sk);

  TailArgs ta;
  ta.Sfp=Sfp; ta.sk=sk; ta.x=x; ta.P=P; ta.X64=X64; ta.pstat0=pstat0;
  ta.pstatA=pstatA; ta.pstatB=pstatB; ta.pstatC=pstatC; ta.sp=sp; ta.sp2=sp2;
  ta.A=A; ta.zf=zf; ta.fd1=fd1; ta.fd2=fd2; ta.out=out;
  ta.n1g=norm1_g; ta.n1b=norm1_b; ta.ag=attn_g; ta.n2g=norm2_g; ta.n2b=norm2_b;
  ta.mng1=mng1; ta.mnb1=mnb1; ta.msw1=msw1; ta.msb1=msb1; ta.mw1=mw1; ta.mw2=mw2;
  ta.mng2=mng2; ta.mnb2=mnb2; ta.msw2=msw2; ta.msb2=msb2; ta.outg=outg; ta.outb=outb;
  ta.ab=attn_b; ta.psw=proj_sw; ta.vsb=value_sb; ta.psb=proj_sb; ta.pw=proj_sw; ta.vw=value_sw;
  void* kargs[] = { &ta };
  hipError_t cerr = hipLaunchCooperativeKernel((const void*)k_tail, dim3(TAIL_GRID), dim3(256),
                                               kargs, 0, stream);
  if (cerr != hipSuccess){
    (void)hipGetLastError();   // clear sticky error, fall back to separate kernels
    k_field0<<<dim3(128,16),256,0,stream>>>(Sfp, sk, x, proj_sw, value_sb, proj_sb, zf, pstatA);
    k_specm0<<<dim3(128,2),256,0,stream>>>(P, proj_sw, value_sw, Sfp, X64, pstat0, pstatA,
        norm1_g, norm1_b, attn_g, norm2_g, norm2_b, proj_sw, value_sb, proj_sb, sp);
    k_field1<<<dim3(128,16),256,0,stream>>>(sp, mw1, fd1, pstatB);
    k_colA1<<<1024,256,0,stream>>>(fd1, zf, pstatA, pstatB, attn_g, norm2_g, mng1,
        norm2_b, mnb1, msw1, msb1, A);
    k_rowfft32<<<dim3(128,4),256,0,stream>>>(A, sp2);
    k_field2<<<dim3(128,16),256,0,stream>>>(sp2, mw2, fd1, zf, pstatA, pstatB,
        attn_g, norm2_g, mng1, norm2_b, mnb1, msw1, msb1, fd2, pstatC);
    k_final2<<<dim3(128,16),256,0,stream>>>(zf, fd1, fd2, pstatA, pstatB, pstatC,
        attn_g, norm2_g, mng1, mng2, outg, attn_b, norm2_b,
        mnb1, msw1, msb1, mnb2, msw2, msb2, outb, out);
  }
}

// Round 12
// 304.776 us; speedup vs baseline: 2.1792x; 2.1792x over previous
//
#include <hip/hip_runtime.h>
#include <cmath>

#define PI_F 3.14159265358979323846f
#define NTOK 128
#define NPIX 16384
#define NHEADS 16

__device__ __forceinline__ void block_reduce2(float& a, float& b){
  __shared__ float sa[4], sb[4];
  __syncthreads();
  for (int o=32;o>0;o>>=1){ a += __shfl_down(a,o); b += __shfl_down(b,o); }
  int w = threadIdx.x>>6, l = threadIdx.x&63;
  if (l==0){ sa[w]=a; sb[w]=b; }
  __syncthreads();
  a = sa[0]+sa[1]+sa[2]+sa[3];
  b = sb[0]+sb[1]+sb[2]+sb[3];
}

__device__ __forceinline__ float block_reduce1(float a){
  __shared__ float sa[4];
  __syncthreads();
  for (int o=32;o>0;o>>=1) a += __shfl_down(a,o);
  int w = threadIdx.x>>6, l = threadIdx.x&63;
  if (l==0) sa[w]=a;
  __syncthreads();
  return sa[0]+sa[1]+sa[2]+sa[3];
}

__device__ __forceinline__ float gelu_f(float y){
  return 0.5f*y*(1.f + erff(y*0.70710678118f));
}

// ---- per-token scalars: pstat0 is 8-slab; pstatA/B/C are 16-slab -----------
__device__ __forceinline__ void affine_from(const float* __restrict__ ps, float g, float bb, int t,
                                            float& a, float& b0){
  float sum=0.f,sq=0.f;
  #pragma unroll
  for (int s=0;s<8;s++){ const float* p=ps+((size_t)t*8+s)*2; sum+=p[0]; sq+=p[1]; }
  const float iN=1.f/NPIX;
  float mu=sum*iN, var=sq*iN-mu*mu;
  a=rsqrtf(var+1e-5f)*g;
  b0=bb-mu*a;
}
__device__ __forceinline__ void scalA_from(const float* __restrict__ psA, float ag, float n2g, int t,
                                           float& muZ, float& aA, float& a0){
  float sum=0.f,sq=0.f;
  #pragma unroll
  for (int s=0;s<16;s++){ const float* p=psA+((size_t)t*16+s)*2; sum+=p[0]; sq+=p[1]; }
  const float iN=1.f/NPIX;
  muZ=sum*iN; float var=sq*iN-muZ*muZ;
  float inv=rsqrtf(var+1e-5f);
  aA=inv*ag;
  float var2=aA*aA*var;
  a0=aA*rsqrtf(var2+1e-5f)*n2g;
}
__device__ __forceinline__ void scalB_from(const float* __restrict__ psB, float mng1, int t,
                                           float& mu1, float& c1){
  float sum=0.f,sq=0.f;
  #pragma unroll
  for (int s=0;s<16;s++){ const float* p=psB+((size_t)t*16+s)*2; sum+=p[0]; sq+=p[1]; }
  const float iN=1.f/NPIX;
  mu1=sum*iN; float var=sq*iN-mu1*mu1;
  c1=rsqrtf(var+1e-5f)*mng1;
}
__device__ __forceinline__ void scalC_from(const float* __restrict__ psC, float mng2, float K, float sw,
                                           float outg, int t,
                                           float& mu2f, float& c2, float& mu3, float& c3){
  float sf=0.f,sfsq=0.f,sm=0.f,smsq=0.f,sx=0.f;
  #pragma unroll
  for (int s=0;s<16;s++){
    const float* p=psC+((size_t)t*16+s)*5;
    sf+=p[0]; sfsq+=p[1]; sm+=p[2]; smsq+=p[3]; sx+=p[4];
  }
  const float iN=1.f/NPIX;
  mu2f=sf*iN; float var2=sfsq*iN-mu2f*mu2f;
  c2=rsqrtf(var2+1e-5f)*mng2;
  float Em1=sm*iN, Em1sq=smsq*iN, Exm=sx*iN;
  float Em2=K+sw*Em1;
  float Em2sq = c2*c2*var2 + sw*sw*Em1sq + K*K
              + 2.f*c2*sw*(Exm - mu2f*Em1) + 2.f*K*sw*Em1;
  float var_m2=Em2sq-Em2*Em2;
  mu3=Em2;
  c3=rsqrtf(var_m2+1e-5f)*outg;
}

// ---- slab stats of x (8 slabs) ---------------------------------------------
__global__ __launch_bounds__(256) void k_stats0(const float* __restrict__ x, float* __restrict__ pstat){
  int t=blockIdx.x, slab=blockIdx.y;
  const float* xs = x + (size_t)t*NPIX + slab*2048;
  float sum=0.f, sq=0.f;
  for (int i=threadIdx.x;i<2048;i+=256){ float v=xs[i]; sum+=v; sq+=v*v; }
  block_reduce2(sum,sq);
  if (threadIdx.x==0){ float* o=pstat+((size_t)t*8+slab)*2; o[0]=sum; o[1]=sq; }
}

// ---- Column DFT of tn (affine-folded inline), 16 rows per block ------------
__global__ __launch_bounds__(256) void k_colfft33(const float* __restrict__ x, const float* __restrict__ pstat0,
                          const float* __restrict__ n1g, const float* __restrict__ n1b,
                          float* __restrict__ A){
  __shared__ float rows[16*128];
  __shared__ float tw[128][2];
  int base = blockIdx.x*16;
  int t = base>>7;
  float a,b0; affine_from(pstat0, n1g[0], n1b[0], t, a, b0);
  for (int i=threadIdx.x;i<2048;i+=256) rows[i] = a*x[(size_t)base*128 + i] + b0;
  for (int p=threadIdx.x;p<128;p+=256){ float sn,cs; sincosf(-(2.f*PI_F/128.f)*(float)p,&sn,&cs); tw[p][0]=cs; tw[p][1]=sn; }
  __syncthreads();
  for (int e=threadIdx.x;e<16*33;e+=256){
    int r=e/33, c=e%33;
    const float* rp=rows+r*128;
    float re=0.f, im=0.f;
    for (int w=0;w<128;w++){
      int p=(c*w)&127;
      float v=rp[w];
      re+=v*tw[p][0]; im+=v*tw[p][1];
    }
    float* o=A+((size_t)(base+r)*33+c)*2; o[0]=re; o[1]=im;
  }
}

// ---- Row DFT -> 64x33 spectrum, column-group parallel ----------------------
__global__ __launch_bounds__(256) void k_rowfft64(const float* __restrict__ A,
                          float* __restrict__ X64, float* __restrict__ X64h){
  int s=blockIdx.x, cg2=blockIdx.y;
  int c0=cg2*11;
  __shared__ float a[128][11][2];
  __shared__ float S[64][11][2];
  __shared__ float tw[128][2];
  for (int i=threadIdx.x;i<128*22;i+=256){
    int r=i/22, q=i%22;
    a[r][q>>1][q&1] = A[((size_t)(s*128+r)*33 + c0)*2 + q];
  }
  for (int p=threadIdx.x;p<128;p+=256){ float sn,cs; sincosf(-(2.f*PI_F/128.f)*(float)p,&sn,&cs); tw[p][0]=cs; tw[p][1]=sn; }
  __syncthreads();
  const float sc=1.f/16384.f;
  for (int e=threadIdx.x;e<64*11;e+=256){
    int i2=e/11, cl=e%11;
    int r=(i2<32)? i2 : i2+64;
    float re=0.f, im=0.f;
    for (int h=0;h<128;h++){
      int p=(r*h)&127;
      float cs=tw[p][0], sn=tw[p][1];
      float ar=a[h][cl][0], ai=a[h][cl][1];
      re+=ar*cs-ai*sn; im+=ar*sn+ai*cs;
    }
    S[i2][cl][0]=re*sc; S[i2][cl][1]=im*sc;
  }
  __syncthreads();
  for (int e=threadIdx.x;e<64*11;e+=256){
    int r=e/11, cl=e%11; int c=c0+cl;
    float vr=S[r][cl][0], vi=S[r][cl][1];
    float* o=X64+((size_t)s*(64*33)+r*33+c)*2; o[0]=vr; o[1]=vi;
    float hr=vr, hi=vi;
    if (c==0 || c==32){
      int pr=(64-r)&63;
      hr=0.5f*(vr+S[pr][cl][0]);
      hi=0.5f*(vi-S[pr][cl][1]);
    }
    float* oh=X64h+((size_t)s*(64*33)+r*33+c)*2; oh[0]=hr; oh[1]=hi;
  }
}

// ---- merged Ue + ZYw (independent stages, block-range branch) --------------
__global__ __launch_bounds__(256) void k_UeZYw(const float* __restrict__ X64, const float* __restrict__ X64h,
    const float* __restrict__ qw, const float* __restrict__ qsw,
    const float* __restrict__ kw, const float* __restrict__ ksw,
    const float* __restrict__ value_w, const float* __restrict__ vsw, const float* __restrict__ vsb,
    const float* __restrict__ proj_w, const float* __restrict__ psw,
    float* __restrict__ Zq, float* __restrict__ Zk, float* __restrict__ Yw,
    float* __restrict__ Ue){
  __shared__ float sh[4224];
  int bx=blockIdx.x;
  if (bx<2048){
    int t=bx>>4, h=bx&15;
    float* Xs = sh;
    float2* xh0 = (float2*)(sh+1092);
    for (int e=threadIdx.x;e<544;e+=256){
      int j=e/17, c=e%17;
      int i2=(j<16)? j : (j+32);
      const float* xp = X64 + ((size_t)t*(64*33) + i2*33 + c)*2;
      Xs[e*2]=xp[0]; Xs[e*2+1]=xp[1];
    }
    if (threadIdx.x<17){
      int j=threadIdx.x;
      int r=(j<=8)? j : j+47;
      const float* hp = X64h + ((size_t)t*(64*33) + r*33)*2;
      xh0[j]=make_float2(hp[0],hp[1]);
    }
    __syncthreads();
    float aq=qsw[h], ak=ksw[h];
    for (int e=threadIdx.x;e<306;e+=256){
      int side=e/153, m=e%153;
      int j=m/9, c=m%9;
      int jj=(j<=8)? j : j+15;
      const float* W = side? kw : qw;
      float a = side? ak : aq;
      float prx=0.f, pry=0.f;
      if (j!=8){
        int jw=(j<8)? j : j-1;
        const float* wp = W + ((size_t)(h*16+jw)*9 + c)*2;
        float xrr=Xs[(jj*17+c)*2], xri=Xs[(jj*17+c)*2+1];
        prx = wp[0]*xrr - wp[1]*xri;
        pry = wp[0]*xri + wp[1]*xrr;
      }
      float Vx=prx, Vy=pry;
      if (c==0){
        int jp = (j==0)? 0 : 17-j;
        float ppx=0.f, ppy=0.f;
        if (jp!=8){
          int jw2=(jp<8)? jp : jp-1;
          const float* wp2 = W + ((size_t)(h*16+jw2)*9)*2;
          int jj2=(jp<=8)? jp : jp+15;
          float x2r=Xs[(jj2*17)*2], x2i=Xs[(jj2*17)*2+1];
          ppx = wp2[0]*x2r - wp2[1]*x2i;
          ppy = wp2[0]*x2i + wp2[1]*x2r;
        }
        Vx = 0.5f*(prx + ppx);
        Vy = 0.5f*(pry - ppy);
      }
      float xmr, xmi;
      if (c==0){ xmr=xh0[j].x; xmi=xh0[j].y; }
      else { xmr=Xs[(jj*17+c)*2]; xmi=Xs[(jj*17+c)*2+1]; }
      float zr = a*xmr + Vx;
      float zi = a*xmi + Vy;
      float wf = (side && c!=0)? 2.f : 1.f;
      float* dst = (side? Zk : Zq) + ((size_t)(t*16+h))*306 + m*2;
      dst[0]=wf*zr; dst[1]=wf*zi;
    }
    int b=t>>5, s=t&31;
    float vw=vsw[h], vb=vsb[h], pw=psw[h];
    size_t obase = ((size_t)(b*16+h)*32 + s)*1088;
    for (int e=threadIdx.x;e<544;e+=256){
      int j=e/17, c=e%17;
      float xr=Xs[e*2], xi=Xs[e*2+1];
      float wvr=0.f,wvi=0.f;
      if (c<=8 && (j<8||j>=24)){
        int jw=(j<8)? j : (j-16);
        const float* wv = value_w + ((size_t)(h*16+jw)*9 + c)*2;
        wvr=wv[0]; wvi=wv[1];
      }
      float Mr=xr*wvr-xi*wvi, Mi=xr*wvi+xi*wvr;
      float Mhr=Mr, Mhi=Mi;
      if (c==0){
        float Pr2=0.f,Pi2=0.f;
        int jp2=(j==0)?0:((j==16)?-1:32-j);
        if (jp2>=0 && (jp2<8||jp2>=24)){
          int jw2=(jp2<8)? jp2 : (jp2-16);
          const float* wv2=value_w+((size_t)(h*16+jw2)*9)*2;
          float pxr=Xs[(jp2*17)*2], pxi=Xs[(jp2*17)*2+1];
          Pr2=pxr*wv2[0]-pxi*wv2[1];
          Pi2=pxr*wv2[1]+pxi*wv2[0];
        }
        Mhr=0.5f*(Mr+Pr2); Mhi=0.5f*(Mi-Pi2);
      }
      float Yr=vw*xr+Mhr+((e==0)? vb:0.f);
      float Yi=vw*xi+Mhi;
      const float* pc=proj_w+((size_t)(h*32+j)*17+c)*2;
      float pr=pc[0], pi=pc[1];
      float* o=Yw+obase+e*2;
      o[0]=pr*Yr-pi*Yi+pw*Mr;
      o[1]=pr*Yi+pi*Yr+pw*Mi;
    }
  } else {
    int u=bx-2048;
    int b=u>>8, rem=u&255, t=rem>>3, sg=rem&7;
    float2* xt=(float2*)sh;
    const float2* src = (const float2*)(X64h + ((size_t)(b*32+t))*4224);
    for (int m=threadIdx.x;m<2112;m+=256){
      int r=m/33, c=m%33;
      bool excl = (c<=8) && (r<=8 || r>=56);
      float w = excl? 0.f : ((c==0||c==32)? 1.f : 2.f);
      float2 v = src[m];
      xt[m]=make_float2(v.x*w, v.y*w);
    }
    __syncthreads();
    float acc[4]={0.f,0.f,0.f,0.f};
    const float2* s0=(const float2*)(X64h + ((size_t)(b*32+sg*4))*4224);
    for (int m=threadIdx.x;m<2112;m+=256){
      float2 a2=xt[m];
      #pragma unroll
      for (int j=0;j<4;j++){
        float2 b2=s0[(size_t)j*2112+m];
        acc[j]+=a2.x*b2.x+a2.y*b2.y;
      }
    }
    for (int j=0;j<4;j++){
      float r=block_reduce1(acc[j]);
      if (threadIdx.x==0) Ue[((size_t)(b*32+t))*32 + sg*4+j]=r;
    }
  }
}

// ---- scores + fused softmax, t-split grid (4,16,2) -------------------------
__global__ __launch_bounds__(256) void k_scores2(const float* __restrict__ Zq, const float* __restrict__ Zk,
                          const float* __restrict__ Ue,
                          const float* __restrict__ qsw, const float* __restrict__ qsb,
                          const float* __restrict__ ksw, const float* __restrict__ ksb,
                          float* __restrict__ P){
  int b=blockIdx.x, h=blockIdx.y, tz=blockIdx.z;
  __shared__ float2 zq[16][154];
  __shared__ float2 zk[16][154];
  __shared__ float Pl[16][33];
  for (int i=threadIdx.x;i<16*153;i+=256){
    int t=i/153, m=i%153;
    zq[t][m]=((const float2*)(Zq + ((size_t)((b*32+tz*16+t)*16+h))*306))[m];
  }
  float aq=qsw[h], ak=ksw[h], bq=qsb[h], bk=ksb[h];
  float aqak=aq*ak;
  int tl=threadIdx.x>>4, sl=threadIdx.x&15;
  for (int ch=0; ch<2; ch++){
    __syncthreads();
    for (int i=threadIdx.x;i<16*153;i+=256){
      int s=i/153, m=i%153;
      zk[s][m]=((const float2*)(Zk + ((size_t)((b*32+ch*16+s)*16+h))*306))[m];
    }
    __syncthreads();
    float acc=0.f;
    for (int m=0;m<153;m++){
      float2 a2=zq[tl][m], c2=zk[sl][m];
      acc += a2.x*c2.x + a2.y*c2.y;
    }
    int s=ch*16+sl;
    float G = aqak*Ue[((size_t)(b*32+tz*16+tl))*32+s] + acc;
    Pl[tl][s] = 64.f*(G + bk*zq[tl][0].x + bq*zk[sl][0].x + bq*bk);
  }
  __syncthreads();
  if (threadIdx.x<16){
    int tt=threadIdx.x;
    float mx=-INFINITY;
    for (int s=0;s<32;s++) mx=fmaxf(mx,Pl[tt][s]);
    float e[32]; float sum=0.f;
    for (int s=0;s<32;s++){ e[s]=expf(Pl[tt][s]-mx); sum+=e[s]; }
    float inv=1.f/sum;
    size_t base=((size_t)(b*16+h)*32+tz*16+tt)*32;
    for (int s=0;s<32;s++) P[base+s]=e[s]*inv;
  }
}

// ---- merged SfC2 + skipmix (both consume P, independent) -------------------
__global__ __launch_bounds__(256) void k_SfSk(const float* __restrict__ x, const float* __restrict__ P,
        const float* __restrict__ Yw,
        const float* __restrict__ pw, const float* __restrict__ vw,
        const float* __restrict__ pstat0, const float* __restrict__ n1g, const float* __restrict__ n1b,
        float* __restrict__ Sfp, float* __restrict__ sk){
  __shared__ float sh[4096];
  int bx=blockIdx.x;
  if (bx<272){
    int b=bx/68, rem=bx%68, ec=rem/4, g=rem%4;
    int e0=ec*64, hs0=g*128;
    float (*Pl)[32] = (float(*)[32])sh;
    for (int i=threadIdx.x;i<128*32;i+=256){
      int hsl=i>>5, t=i&31;
      int hs=hs0+hsl, h=hs>>5, s=hs&31;
      Pl[hsl][t]=P[(((size_t)(b*16+h)*32)+t)*32+s];
    }
    __syncthreads();
    int el=threadIdx.x&63, tg=threadIdx.x>>6;
    float acc[8];
    #pragma unroll
    for (int j=0;j<8;j++) acc[j]=0.f;
    const float* Yb = Yw + ((size_t)b*512 + hs0)*1088 + e0 + el;
    #pragma unroll 4
    for (int hsl=0;hsl<128;hsl++){
      float y = Yb[(size_t)hsl*1088];
      #pragma unroll
      for (int j=0;j<8;j++) acc[j] += Pl[hsl][tg*8+j]*y;
    }
    #pragma unroll
    for (int j=0;j<8;j++){
      int t=tg*8+j;
      Sfp[((size_t)(b*32+t)*4+g)*1088 + e0 + el] = acc[j];
    }
  } else {
    int u=bx-272;
    int b=u>>6, rem=u&63, ch=rem>>1, tt=rem&1;
    int pxb=ch*512;
    float* Rs = sh;
    float* cbs = sh+512;
    float* as2 = sh+528;
    float* b0s = sh+560;
    if (threadIdx.x<32){
      float a,b0; affine_from(pstat0, n1g[0], n1b[0], b*32+threadIdx.x, a, b0);
      as2[threadIdx.x]=a; b0s[threadIdx.x]=b0;
    }
    __syncthreads();
    for (int rr=threadIdx.x; rr<512; rr+=256){
      int tl=rr>>5, s=rr&31;
      int t=tt*16+tl;
      float acc=0.f;
      for (int h=0;h<16;h++)
        acc += pw[h]*vw[h]*P[(((size_t)(b*16+h)*32)+t)*32+s];
      Rs[tl*32+s]=acc*as2[s];
      float cb=acc*b0s[s];
      for (int o=16;o>0;o>>=1) cb+=__shfl_down(cb,o,32);
      if (s==0) cbs[tl]=cb;
    }
    __syncthreads();
    float a0[16], a1[16];
    #pragma unroll
    for (int t=0;t<16;t++){ a0[t]=0.f; a1[t]=0.f; }
    for (int s=0;s<32;s++){
      const float* xp = x + ((size_t)(b*32+s))*NPIX + pxb;
      float v0=xp[threadIdx.x], v1=xp[threadIdx.x+256];
      #pragma unroll
      for (int t=0;t<16;t++){ float r=Rs[t*32+s]; a0[t]+=r*v0; a1[t]+=r*v1; }
    }
    #pragma unroll
    for (int t=0;t<16;t++){
      int gt=tt*16+t;
      float cb=cbs[t];
      float* op = sk + ((size_t)(b*32+gt))*NPIX + pxb;
      op[threadIdx.x]=a0[t]+cb; op[threadIdx.x+256]=a1[t]+cb;
    }
  }
}

// ---- proj field (16 slabs): zf = irfft(sum Sfp) + sk + x + Cb --------------
__global__ __launch_bounds__(256) void k_field0(const float* __restrict__ Sfp,
        const float* __restrict__ sk, const float* __restrict__ x,
        const float* __restrict__ psw, const float* __restrict__ vsb, const float* __restrict__ psb,
        float* __restrict__ zf, float* __restrict__ pstatA){
  int bt = blockIdx.x, slab = blockIdx.y;
  __shared__ float Ss[1088];
  __shared__ float T[8*17*2];
  __shared__ float tw[128][2];
  for (int i=threadIdx.x;i<1088;i+=256){
    const float* sp4 = Sfp + (size_t)bt*4352 + i;
    Ss[i] = sp4[0]+sp4[1088]+sp4[2176]+sp4[3264];
  }
  for (int p=threadIdx.x;p<128;p+=256){ float sn,cs; sincosf((2.f*PI_F/128.f)*(float)p,&sn,&cs); tw[p][0]=cs; tw[p][1]=sn; }
  __syncthreads();
  int h0 = slab*8;
  for (int e=threadIdx.x;e<8*17;e+=256){
    int hl=e/17, c=e%17; int h=h0+hl;
    float re=0.f, im=0.f;
    for (int j=0;j<32;j++){
      int r=(j<16)? j : (j+96);
      int p=(r*h)&127;
      float cs=tw[p][0], sn=tw[p][1];
      float ar=Ss[(j*17+c)*2], ai=Ss[(j*17+c)*2+1];
      re += ar*cs - ai*sn;
      im += ar*sn + ai*cs;
    }
    T[e*2]=re; T[e*2+1]=im;
  }
  __syncthreads();
  size_t base = (size_t)bt*NPIX + h0*128;
  float Cb = psb[0];
  for (int hh=0;hh<16;hh++) Cb += psw[hh]*vsb[hh];
  float sum=0.f, sq=0.f;
  for (int pos=threadIdx.x;pos<1024;pos+=256){
    int hl=pos>>7, w=pos&127;
    const float* Th=T+hl*17*2;
    float br=tw[w][0], bi=tw[w][1];
    float rr=br, ri=bi;
    float v=Th[0];
    for (int c=1;c<17;c++){
      v += 2.f*(Th[c*2]*rr - Th[c*2+1]*ri);
      float nr=rr*br-ri*bi; ri=rr*bi+ri*br; rr=nr;
    }
    float val = v + sk[base+pos] + x[base+pos] + Cb;
    zf[base+pos]=val; sum+=val; sq+=val*val;
  }
  block_reduce2(sum,sq);
  if (threadIdx.x==0){ float* o=pstatA+((size_t)bt*16+slab)*2; o[0]=sum; o[1]=sq; }
}

// ---- spectral shortcut: spec(m0), e-split grid (128,2) ---------------------
__global__ __launch_bounds__(256) void k_specm0(const float* __restrict__ P,
    const float* __restrict__ pw, const float* __restrict__ vw,
    const float* __restrict__ Sfp, const float* __restrict__ X64,
    const float* __restrict__ pstat0, const float* __restrict__ pstatA,
    const float* __restrict__ n1g, const float* __restrict__ n1b,
    const float* __restrict__ ag, const float* __restrict__ n2g, const float* __restrict__ n2b,
    const float* __restrict__ psw, const float* __restrict__ vsb, const float* __restrict__ psb,
    float* __restrict__ sp){
  int bt=blockIdx.x, ec=blockIdx.y; int b=bt>>5, t=bt&31;
  __shared__ float Rs[32];
  __shared__ float Sfl[1088];
  if (threadIdx.x<32){
    int s=threadIdx.x; float acc=0.f;
    for (int h=0;h<16;h++)
      acc += pw[h]*vw[h]*P[(((size_t)(b*16+h)*32)+t)*32+s];
    Rs[s]=acc;
  }
  for (int i=threadIdx.x;i<1088;i+=256){
    const float* sp4 = Sfp + (size_t)bt*4352 + i;
    Sfl[i]=sp4[0]+sp4[1088]+sp4[2176]+sp4[3264];
  }
  __syncthreads();
  float a_t,b0_t; affine_from(pstat0,n1g[0],n1b[0],bt,a_t,b0_t);
  float muZ,aA,a0; scalA_from(pstatA,ag[0],n2g[0],bt,muZ,aA,a0);
  float Cb=psb[0];
  for (int h=0;h<16;h++) Cb+=psw[h]*vsb[h];
  float inva=1.f/a_t;
  int e1=ec*272, e2=e1+272;
  for (int e=e1+threadIdx.x;e<e2;e+=256){
    int j=e/17, c=e%17;
    float sr=Sfl[e*2], si=Sfl[e*2+1];
    if (c==0){
      if (j==0){ si=0.f; }
      else if (j==16){ sr*=0.5f; si*=0.5f; }
      else { int jp=32-j; sr=0.5f*(sr+Sfl[jp*34]); si=0.5f*(si-Sfl[jp*34+1]); }
    }
    int i2=(j<16)? j : (j+32);
    float re=0.f, im=0.f;
    const float* xb = X64 + ((size_t)(b*32)*(64*33) + i2*33 + c)*2;
    for (int s=0;s<32;s++){
      const float* xp = xb + (size_t)s*(64*33)*2;
      float r=Rs[s];
      re += r*xp[0]; im += r*xp[1];
    }
    const float* xt = X64 + ((size_t)bt*(64*33) + i2*33 + c)*2;
    re += inva*xt[0]; im += inva*xt[1];
    float zr=sr+re, zi=si+im;
    if (e==0) zr += Cb - b0_t*inva;
    float mr=a0*zr, mi=a0*zi;
    if (e==0) mr += n2b[0] - muZ*a0;
    sp[((size_t)bt*544+e)*2]=mr; sp[((size_t)bt*544+e)*2+1]=mi;
  }
}

// ---- mixer1 field (16 slabs): fd1 = irfft(sp * mw1) ------------------------
__global__ __launch_bounds__(256) void k_field1(const float* __restrict__ sp, const float* __restrict__ wm,
        float* __restrict__ fd1, float* __restrict__ pstatB){
  int bt = blockIdx.x, slab = blockIdx.y;
  __shared__ float Ss[1088];
  __shared__ float T[8*17*2];
  __shared__ float tw[128][2];
  for (int e=threadIdx.x;e<544;e+=256){
    float xr=sp[((size_t)bt*544+e)*2], xi=sp[((size_t)bt*544+e)*2+1];
    float wr=wm[e*2], wi=wm[e*2+1];
    Ss[e*2]=xr*wr-xi*wi; Ss[e*2+1]=xr*wi+xi*wr;
  }
  for (int p=threadIdx.x;p<128;p+=256){ float sn,cs; sincosf((2.f*PI_F/128.f)*(float)p,&sn,&cs); tw[p][0]=cs; tw[p][1]=sn; }
  __syncthreads();
  int h0 = slab*8;
  for (int e=threadIdx.x;e<8*17;e+=256){
    int hl=e/17, c=e%17; int h=h0+hl;
    float re=0.f, im=0.f;
    for (int j=0;j<32;j++){
      int r=(j<16)? j : (j+96);
      int p=(r*h)&127;
      float cs=tw[p][0], sn=tw[p][1];
      float ar=Ss[(j*17+c)*2], ai=Ss[(j*17+c)*2+1];
      re += ar*cs - ai*sn;
      im += ar*sn + ai*cs;
    }
    T[e*2]=re; T[e*2+1]=im;
  }
  __syncthreads();
  size_t base = (size_t)bt*NPIX + h0*128;
  float sum=0.f, sq=0.f;
  for (int pos=threadIdx.x;pos<1024;pos+=256){
    int hl=pos>>7, w=pos&127;
    const float* Th=T+hl*17*2;
    float br=tw[w][0], bi=tw[w][1];
    float rr=br, ri=bi;
    float v=Th[0];
    for (int c=1;c<17;c++){
      v += 2.f*(Th[c*2]*rr - Th[c*2+1]*ri);
      float nr=rr*br-ri*bi; ri=rr*bi+ri*br; rr=nr;
    }
    fd1[base+pos]=v; sum+=v; sq+=v*v;
  }
  block_reduce2(sum,sq);
  if (threadIdx.x==0){ float* o=pstatB+((size_t)bt*16+slab)*2; o[0]=sum; o[1]=sq; }
}

// ---- column DFT of m1 (recomputed on the fly), 16 rows per block -----------
__global__ __launch_bounds__(256) void k_colA1(const float* __restrict__ f1, const float* __restrict__ z,
        const float* __restrict__ pstatA, const float* __restrict__ pstatB,
        const float* __restrict__ ag, const float* __restrict__ n2g, const float* __restrict__ mng1,
        const float* __restrict__ n2b,
        const float* __restrict__ mnb1, const float* __restrict__ msw1, const float* __restrict__ msb1,
        float* __restrict__ A){
  __shared__ float rows[16*128];
  __shared__ float tw[128][2];
  int grow = blockIdx.x*16;
  int t = grow>>7;
  float muZ,aA,a0;
  scalA_from(pstatA, ag[0], n2g[0], t, muZ, aA, a0);
  float b2 = n2b[0];
  float mu1,c1;
  scalB_from(pstatB, mng1[0], t, mu1, c1);
  float nb=mnb1[0], sw=msw1[0], sb=msb1[0];
  for (int i=threadIdx.x;i<2048;i+=256){
    size_t gi=(size_t)grow*128+i;
    float m0v=(z[gi]-muZ)*a0+b2;
    float y=(f1[gi]-mu1)*c1+nb + m0v*sw + sb;
    rows[i]=gelu_f(y);
  }
  for (int p=threadIdx.x;p<128;p+=256){ float sn,cs; sincosf(-(2.f*PI_F/128.f)*(float)p,&sn,&cs); tw[p][0]=cs; tw[p][1]=sn; }
  __syncthreads();
  for (int e=threadIdx.x;e<16*17;e+=256){
    int r=e/17, c=e%17;
    const float* rp=rows+r*128;
    float re=0.f, im=0.f;
    for (int w=0;w<128;w++){
      int p=(c*w)&127;
      float v=rp[w];
      re+=v*tw[p][0]; im+=v*tw[p][1];
    }
    float* o=A+((size_t)(grow+r)*17+c)*2; o[0]=re; o[1]=im;
  }
}

// ---- forward 32x17 modes, column-group parallel ----------------------------
__global__ __launch_bounds__(256) void k_rowfft32(const float* __restrict__ A, float* __restrict__ spec){
  int s=blockIdx.x, cg2=blockIdx.y;
  int c0 = (cg2==0)? 0 : (1+cg2*4);
  int nc = (cg2==0)? 5 : 4;
  __shared__ float a[128*5*2];
  __shared__ float tw[128][2];
  for (int i=threadIdx.x;i<128*nc*2;i+=256){
    int r=i/(2*nc), q=i%(2*nc);
    a[(r*5+(q>>1))*2+(q&1)] = A[((size_t)(s*128+r)*17 + c0)*2 + q];
  }
  for (int p=threadIdx.x;p<128;p+=256){ float sn,cs; sincosf(-(2.f*PI_F/128.f)*(float)p,&sn,&cs); tw[p][0]=cs; tw[p][1]=sn; }
  __syncthreads();
  const float sc=1.f/16384.f;
  for (int e=threadIdx.x;e<32*nc;e+=256){
    int j=e/nc, cl=e%nc;
    int r=(j<16)? j : (j+96);
    float re=0.f,im=0.f;
    for (int h=0;h<128;h++){
      int p=(r*h)&127;
      float cs=tw[p][0], sn=tw[p][1];
      float ar=a[(h*5+cl)*2], ai=a[(h*5+cl)*2+1];
      re += ar*cs - ai*sn;
      im += ar*sn + ai*cs;
    }
    float* o=spec+((size_t)s*544 + j*17 + c0+cl)*2;
    o[0]=re*sc; o[1]=im*sc;
  }
}

// ---- mixer2 field (16 slabs): fd2 = irfft(sp2 * mw2); cross-moment stats ---
__global__ __launch_bounds__(256) void k_field2(const float* __restrict__ sp2, const float* __restrict__ wm,
        const float* __restrict__ f1, const float* __restrict__ z,
        const float* __restrict__ pstatA, const float* __restrict__ pstatB,
        const float* __restrict__ ag, const float* __restrict__ n2g, const float* __restrict__ mng1,
        const float* __restrict__ n2b, const float* __restrict__ mnb1,
        const float* __restrict__ msw1, const float* __restrict__ msb1,
        float* __restrict__ fd2, float* __restrict__ pstatC){
  int bt = blockIdx.x, slab = blockIdx.y;
  __shared__ float Ss[1088];
  __shared__ float T[8*17*2];
  __shared__ float tw[128][2];
  for (int e=threadIdx.x;e<544;e+=256){
    float xr=sp2[((size_t)bt*544+e)*2], xi=sp2[((size_t)bt*544+e)*2+1];
    float wr=wm[e*2], wi=wm[e*2+1];
    Ss[e*2]=xr*wr-xi*wi; Ss[e*2+1]=xr*wi+xi*wr;
  }
  for (int p=threadIdx.x;p<128;p+=256){ float sn,cs; sincosf((2.f*PI_F/128.f)*(float)p,&sn,&cs); tw[p][0]=cs; tw[p][1]=sn; }
  __syncthreads();
  int h0 = slab*8;
  for (int e=threadIdx.x;e<8*17;e+=256){
    int hl=e/17, c=e%17; int h=h0+hl;
    float re=0.f, im=0.f;
    for (int j=0;j<32;j++){
      int r=(j<16)? j : (j+96);
      int p=(r*h)&127;
      float cs=tw[p][0], sn=tw[p][1];
      float ar=Ss[(j*17+c)*2], ai=Ss[(j*17+c)*2+1];
      re += ar*cs - ai*sn;
      im += ar*sn + ai*cs;
    }
    T[e*2]=re; T[e*2+1]=im;
  }
  __syncthreads();
  size_t base = (size_t)bt*NPIX + h0*128;
  float muZ,aA,a0,mu1,c1;
  scalA_from(pstatA, ag[0], n2g[0], bt, muZ, aA, a0);
  scalB_from(pstatB, mng1[0], bt, mu1, c1);
  float b2=n2b[0], nb1=mnb1[0], sw1=msw1[0], sb1=msb1[0];
  float s_f=0.f,s_fsq=0.f,s_m=0.f,s_msq=0.f,s_x=0.f;
  for (int pos=threadIdx.x;pos<1024;pos+=256){
    int hl=pos>>7, w=pos&127;
    const float* Th=T+hl*17*2;
    float br=tw[w][0], bi=tw[w][1];
    float rr=br, ri=bi;
    float v=Th[0];
    for (int c=1;c<17;c++){
      v += 2.f*(Th[c*2]*rr - Th[c*2+1]*ri);
      float nr=rr*br-ri*bi; ri=rr*bi+ri*br; rr=nr;
    }
    size_t gi=base+pos;
    float m0v=(z[gi]-muZ)*a0+b2;
    float y=(f1[gi]-mu1)*c1+nb1 + m0v*sw1 + sb1;
    float m1v=gelu_f(y);
    fd2[gi]=v;
    s_f+=v; s_fsq+=v*v; s_m+=m1v; s_msq+=m1v*m1v; s_x+=v*m1v;
  }
  block_reduce2(s_f,s_fsq);
  block_reduce2(s_m,s_msq);
  s_x = block_reduce1(s_x);
  if (threadIdx.x==0){
    float* o=pstatC+((size_t)bt*16+slab)*5;
    o[0]=s_f; o[1]=s_fsq; o[2]=s_m; o[3]=s_msq; o[4]=s_x;
  }
}

// ---- final (16 slabs): out = norm(m2)+a2, scalars inline -------------------
__global__ __launch_bounds__(256) void k_final2(const float* __restrict__ z, const float* __restrict__ f1,
        const float* __restrict__ f2,
        const float* __restrict__ pstatA, const float* __restrict__ pstatB, const float* __restrict__ pstatC,
        const float* __restrict__ ag, const float* __restrict__ n2g, const float* __restrict__ mng1,
        const float* __restrict__ mng2, const float* __restrict__ outg,
        const float* __restrict__ ab, const float* __restrict__ n2b,
        const float* __restrict__ mnb1, const float* __restrict__ msw1, const float* __restrict__ msb1,
        const float* __restrict__ mnb2, const float* __restrict__ msw2, const float* __restrict__ msb2,
        const float* __restrict__ outb, float* __restrict__ out){
  int bt=blockIdx.x, slab=blockIdx.y;
  float muZ,aA,a0,mu1,c1,mu2f,c2,mu3,c3;
  scalA_from(pstatA, ag[0], n2g[0], bt, muZ, aA, a0);
  scalB_from(pstatB, mng1[0], bt, mu1, c1);
  float sw2=msw2[0], K=mnb2[0]+msb2[0];
  scalC_from(pstatC, mng2[0], K, sw2, outg[0], bt, mu2f, c2, mu3, c3);
  float b1=ab[0], b2=n2b[0], nb1=mnb1[0], sw1=msw1[0], sb1=msb1[0];
  float nb2=mnb2[0], sb2=msb2[0], bo=outb[0];
  size_t base=(size_t)bt*NPIX + (size_t)slab*1024;
  for (int i=threadIdx.x;i<1024;i+=256){
    size_t gi=base+i;
    float zv=z[gi];
    float m0v=(zv-muZ)*a0+b2;
    float a2v=(zv-muZ)*aA+b1;
    float y=(f1[gi]-mu1)*c1+nb1 + m0v*sw1 + sb1;
    float m1v=gelu_f(y);
    float m2v=(f2[gi]-mu2f)*c2+nb2 + m1v*sw2 + sb2;
    out[gi]=(m2v-mu3)*c3+bo+a2v;
  }
}

extern "C" void kernel_launch(void* const* d_in, const int* in_sizes, int n_in,
                              void* d_out, int out_size, void* d_ws, size_t ws_size,
                              hipStream_t stream){
  const float* x        = (const float*)d_in[0];
  const float* key_w    = (const float*)d_in[1];
  const float* key_sw   = (const float*)d_in[2];
  const float* key_sb   = (const float*)d_in[3];
  const float* query_w  = (const float*)d_in[4];
  const float* query_sw = (const float*)d_in[5];
  const float* query_sb = (const float*)d_in[6];
  const float* value_w  = (const float*)d_in[7];
  const float* value_sw = (const float*)d_in[8];
  const float* value_sb = (const float*)d_in[9];
  const float* proj_w   = (const float*)d_in[10];
  const float* proj_sw  = (const float*)d_in[11];
  const float* proj_sb  = (const float*)d_in[12];
  const float* norm1_g  = (const float*)d_in[13];
  const float* norm1_b  = (const float*)d_in[14];
  const float* attn_g   = (const float*)d_in[15];
  const float* attn_b   = (const float*)d_in[16];
  const float* norm2_g  = (const float*)d_in[17];
  const float* norm2_b  = (const float*)d_in[18];
  const float* mw1      = (const float*)d_in[19];
  const float* msw1     = (const float*)d_in[20];
  const float* msb1     = (const float*)d_in[21];
  const float* mng1     = (const float*)d_in[22];
  const float* mnb1     = (const float*)d_in[23];
  const float* mw2      = (const float*)d_in[24];
  const float* msw2     = (const float*)d_in[25];
  const float* msb2     = (const float*)d_in[26];
  const float* mng2     = (const float*)d_in[27];
  const float* mnb2     = (const float*)d_in[28];
  const float* outg     = (const float*)d_in[29];
  const float* outb     = (const float*)d_in[30];
  float* out = (float*)d_out;
  float* ws  = (float*)d_ws;

  size_t off=0;
  float* A   = ws + off; off += (size_t)128*128*33*2;
  float* X64 = ws + off; off += (size_t)128*64*33*2;
  float* X64h= ws + off; off += (size_t)128*64*33*2;
  float* Zq  = ws + off; off += (size_t)128*16*306;
  float* Zk  = ws + off; off += (size_t)128*16*306;
  float* Ue  = ws + off; off += (size_t)4*32*32;
  float* P   = ws + off; off += (size_t)4*16*32*32;
  float* Yw  = ws + off; off += (size_t)2048*1088;
  float* Sfp = ws + off; off += (size_t)128*4*1088;
  float* sk  = ws + off; off += (size_t)128*16384;
  float* zf  = ws + off; off += (size_t)128*16384;
  float* fd1 = ws + off; off += (size_t)128*16384;
  float* fd2 = ws + off; off += (size_t)128*16384;
  float* sp  = ws + off; off += (size_t)128*544*2;
  float* sp2 = ws + off; off += (size_t)128*544*2;
  float* pstat0 = ws + off; off += (size_t)128*8*2;
  float* pstatA = ws + off; off += (size_t)128*16*2;
  float* pstatB = ws + off; off += (size_t)128*16*2;
  float* pstatC = ws + off; off += (size_t)128*16*5;

  k_stats0<<<dim3(128,8),256,0,stream>>>(x, pstat0);
  k_colfft33<<<1024,256,0,stream>>>(x, pstat0, norm1_g, norm1_b, A);
  k_rowfft64<<<dim3(128,3),256,0,stream>>>(A, X64, X64h);
  k_UeZYw<<<3072,256,0,stream>>>(X64, X64h, query_w, query_sw, key_w, key_sw,
      value_w, value_sw, value_sb, proj_w, proj_sw, Zq, Zk, Yw, Ue);
  k_scores2<<<dim3(4,16,2),256,0,stream>>>(Zq, Zk, Ue, query_sw, query_sb, key_sw, key_sb, P);
  k_SfSk<<<528,256,0,stream>>>(x, P, Yw, proj_sw, value_sw, pstat0, norm1_g, norm1_b, Sfp, sk);

  k_field0<<<dim3(128,16),256,0,stream>>>(Sfp, sk, x, proj_sw, value_sb, proj_sb, zf, pstatA);
  k_specm0<<<dim3(128,2),256,0,stream>>>(P, proj_sw, value_sw, Sfp, X64, pstat0, pstatA,
      norm1_g, norm1_b, attn_g, norm2_g, norm2_b, proj_sw, value_sb, proj_sb, sp);
  k_field1<<<dim3(128,16),256,0,stream>>>(sp, mw1, fd1, pstatB);
  k_colA1<<<1024,256,0,stream>>>(fd1, zf, pstatA, pstatB, attn_g, norm2_g, mng1,
      norm2_b, mnb1, msw1, msb1, A);
  k_rowfft32<<<dim3(128,4),256,0,stream>>>(A, sp2);
  k_field2<<<dim3(128,16),256,0,stream>>>(sp2, mw2, fd1, zf, pstatA, pstatB,
      attn_g, norm2_g, mng1, norm2_b, mnb1, msw1, msb1, fd2, pstatC);
  k_final2<<<dim3(128,16),256,0,stream>>>(zf, fd1, fd2, pstatA, pstatB, pstatC,
      attn_g, norm2_g, mng1, mng2, outg, attn_b, norm2_b,
      mnb1, msw1, msb1, mnb2, msw2, msb2, outb, out);
}

// Round 13
// 301.856 us; speedup vs baseline: 2.2003x; 1.0097x over previous
//
#include <hip/hip_runtime.h>
#include <cmath>

#define PI_F 3.14159265358979323846f
#define NTOK 128
#define NPIX 16384
#define NHEADS 16

__device__ __forceinline__ void block_reduce2(float& a, float& b){
  __shared__ float sa[4], sb[4];
  __syncthreads();
  for (int o=32;o>0;o>>=1){ a += __shfl_down(a,o); b += __shfl_down(b,o); }
  int w = threadIdx.x>>6, l = threadIdx.x&63;
  if (l==0){ sa[w]=a; sb[w]=b; }
  __syncthreads();
  a = sa[0]+sa[1]+sa[2]+sa[3];
  b = sb[0]+sb[1]+sb[2]+sb[3];
}

__device__ __forceinline__ float block_reduce1(float a){
  __shared__ float sa[4];
  __syncthreads();
  for (int o=32;o>0;o>>=1) a += __shfl_down(a,o);
  int w = threadIdx.x>>6, l = threadIdx.x&63;
  if (l==0) sa[w]=a;
  __syncthreads();
  return sa[0]+sa[1]+sa[2]+sa[3];
}

__device__ __forceinline__ float gelu_f(float y){
  return 0.5f*y*(1.f + erff(y*0.70710678118f));
}

// ---- per-token scalars: pstat0 is 8-slab; pstatA/B/C are 16-slab -----------
__device__ __forceinline__ void affine_from(const float* __restrict__ ps, float g, float bb, int t,
                                            float& a, float& b0){
  float sum=0.f,sq=0.f;
  #pragma unroll
  for (int s=0;s<8;s++){ const float* p=ps+((size_t)t*8+s)*2; sum+=p[0]; sq+=p[1]; }
  const float iN=1.f/NPIX;
  float mu=sum*iN, var=sq*iN-mu*mu;
  a=rsqrtf(var+1e-5f)*g;
  b0=bb-mu*a;
}
__device__ __forceinline__ void scalA_from(const float* __restrict__ psA, float ag, float n2g, int t,
                                           float& muZ, float& aA, float& a0){
  float sum=0.f,sq=0.f;
  #pragma unroll
  for (int s=0;s<16;s++){ const float* p=psA+((size_t)t*16+s)*2; sum+=p[0]; sq+=p[1]; }
  const float iN=1.f/NPIX;
  muZ=sum*iN; float var=sq*iN-muZ*muZ;
  float inv=rsqrtf(var+1e-5f);
  aA=inv*ag;
  float var2=aA*aA*var;
  a0=aA*rsqrtf(var2+1e-5f)*n2g;
}
__device__ __forceinline__ void scalB_from(const float* __restrict__ psB, float mng1, int t,
                                           float& mu1, float& c1){
  float sum=0.f,sq=0.f;
  #pragma unroll
  for (int s=0;s<16;s++){ const float* p=psB+((size_t)t*16+s)*2; sum+=p[0]; sq+=p[1]; }
  const float iN=1.f/NPIX;
  mu1=sum*iN; float var=sq*iN-mu1*mu1;
  c1=rsqrtf(var+1e-5f)*mng1;
}
__device__ __forceinline__ void scalC_from(const float* __restrict__ psC, float mng2, float K, float sw,
                                           float outg, int t,
                                           float& mu2f, float& c2, float& mu3, float& c3){
  float sf=0.f,sfsq=0.f,sm=0.f,smsq=0.f,sx=0.f;
  #pragma unroll
  for (int s=0;s<16;s++){
    const float* p=psC+((size_t)t*16+s)*5;
    sf+=p[0]; sfsq+=p[1]; sm+=p[2]; smsq+=p[3]; sx+=p[4];
  }
  const float iN=1.f/NPIX;
  mu2f=sf*iN; float var2=sfsq*iN-mu2f*mu2f;
  c2=rsqrtf(var2+1e-5f)*mng2;
  float Em1=sm*iN, Em1sq=smsq*iN, Exm=sx*iN;
  float Em2=K+sw*Em1;
  float Em2sq = c2*c2*var2 + sw*sw*Em1sq + K*K
              + 2.f*c2*sw*(Exm - mu2f*Em1) + 2.f*K*sw*Em1;
  float var_m2=Em2sq-Em2*Em2;
  mu3=Em2;
  c3=rsqrtf(var_m2+1e-5f)*outg;
}

// ---- merged: column DFT of RAW x (blocks 0..1023) + slab stats (1024..2047)
__global__ __launch_bounds__(256) void k_scol(const float* __restrict__ x,
                        float* __restrict__ A, float* __restrict__ pstat){
  __shared__ float sh[2304];
  int bx=blockIdx.x;
  if (bx<1024){
    float* rows = sh;             // 2048
    float* tw = sh+2048;          // 256
    int base = bx*16;
    for (int i=threadIdx.x;i<2048;i+=256) rows[i] = x[(size_t)base*128 + i];
    for (int p=threadIdx.x;p<128;p+=256){ float sn,cs; sincosf(-(2.f*PI_F/128.f)*(float)p,&sn,&cs); tw[p*2]=cs; tw[p*2+1]=sn; }
    __syncthreads();
    for (int e=threadIdx.x;e<16*33;e+=256){
      int r=e/33, c=e%33;
      const float* rp=rows+r*128;
      float re=0.f, im=0.f;
      for (int w=0;w<128;w++){
        int p=(c*w)&127;
        float v=rp[w];
        re+=v*tw[p*2]; im+=v*tw[p*2+1];
      }
      float* o=A+((size_t)(base+r)*33+c)*2; o[0]=re; o[1]=im;
    }
  } else {
    int u=bx-1024; int t=u>>3, slab=u&7;
    const float* xs = x + (size_t)t*NPIX + slab*2048;
    float sum=0.f, sq=0.f;
    for (int i=threadIdx.x;i<2048;i+=256){ float v=xs[i]; sum+=v; sq+=v*v; }
    block_reduce2(sum,sq);
    if (threadIdx.x==0){ float* o=pstat+((size_t)t*8+slab)*2; o[0]=sum; o[1]=sq; }
  }
}

// ---- Row DFT -> 64x33 spectrum of tn, affine applied spectrally ------------
__global__ __launch_bounds__(256) void k_rowfft64(const float* __restrict__ A,
                          const float* __restrict__ pstat0,
                          const float* __restrict__ n1g, const float* __restrict__ n1b,
                          float* __restrict__ X64, float* __restrict__ X64h){
  int s=blockIdx.x, cg2=blockIdx.y;
  int c0=cg2*11;
  __shared__ float a[128][11][2];
  __shared__ float S[64][11][2];
  __shared__ float tw[128][2];
  for (int i=threadIdx.x;i<128*22;i+=256){
    int r=i/22, q=i%22;
    a[r][q>>1][q&1] = A[((size_t)(s*128+r)*33 + c0)*2 + q];
  }
  for (int p=threadIdx.x;p<128;p+=256){ float sn,cs; sincosf(-(2.f*PI_F/128.f)*(float)p,&sn,&cs); tw[p][0]=cs; tw[p][1]=sn; }
  float af,b0; affine_from(pstat0, n1g[0], n1b[0], s, af, b0);
  __syncthreads();
  const float sc=1.f/16384.f;
  for (int e=threadIdx.x;e<64*11;e+=256){
    int i2=e/11, cl=e%11;
    int r=(i2<32)? i2 : i2+64;
    float re=0.f, im=0.f;
    for (int h=0;h<128;h++){
      int p=(r*h)&127;
      float cs=tw[p][0], sn=tw[p][1];
      float ar=a[h][cl][0], ai=a[h][cl][1];
      re+=ar*cs-ai*sn; im+=ar*sn+ai*cs;
    }
    // tn-spectrum = af * x-spectrum + b0 at the DC mode only
    float vr = af*re*sc, vi = af*im*sc;
    if (r==0 && (c0+cl)==0) vr += b0;
    S[i2][cl][0]=vr; S[i2][cl][1]=vi;
  }
  __syncthreads();
  for (int e=threadIdx.x;e<64*11;e+=256){
    int r=e/11, cl=e%11; int c=c0+cl;
    float vr=S[r][cl][0], vi=S[r][cl][1];
    float* o=X64+((size_t)s*(64*33)+r*33+c)*2; o[0]=vr; o[1]=vi;
    float hr=vr, hi=vi;
    if (c==0 || c==32){
      int pr=(64-r)&63;
      hr=0.5f*(vr+S[pr][cl][0]);
      hi=0.5f*(vi-S[pr][cl][1]);
    }
    float* oh=X64h+((size_t)s*(64*33)+r*33+c)*2; oh[0]=hr; oh[1]=hi;
  }
}

// ---- merged Ue + ZYw (independent stages, block-range branch) --------------
__global__ __launch_bounds__(256) void k_UeZYw(const float* __restrict__ X64, const float* __restrict__ X64h,
    const float* __restrict__ qw, const float* __restrict__ qsw,
    const float* __restrict__ kw, const float* __restrict__ ksw,
    const float* __restrict__ value_w, const float* __restrict__ vsw, const float* __restrict__ vsb,
    const float* __restrict__ proj_w, const float* __restrict__ psw,
    float* __restrict__ Zq, float* __restrict__ Zk, float* __restrict__ Yw,
    float* __restrict__ Ue){
  __shared__ float sh[4224];
  int bx=blockIdx.x;
  if (bx<2048){
    int t=bx>>4, h=bx&15;
    float* Xs = sh;
    float2* xh0 = (float2*)(sh+1092);
    for (int e=threadIdx.x;e<544;e+=256){
      int j=e/17, c=e%17;
      int i2=(j<16)? j : (j+32);
      const float* xp = X64 + ((size_t)t*(64*33) + i2*33 + c)*2;
      Xs[e*2]=xp[0]; Xs[e*2+1]=xp[1];
    }
    if (threadIdx.x<17){
      int j=threadIdx.x;
      int r=(j<=8)? j : j+47;
      const float* hp = X64h + ((size_t)t*(64*33) + r*33)*2;
      xh0[j]=make_float2(hp[0],hp[1]);
    }
    __syncthreads();
    float aq=qsw[h], ak=ksw[h];
    for (int e=threadIdx.x;e<306;e+=256){
      int side=e/153, m=e%153;
      int j=m/9, c=m%9;
      int jj=(j<=8)? j : j+15;
      const float* W = side? kw : qw;
      float a = side? ak : aq;
      float prx=0.f, pry=0.f;
      if (j!=8){
        int jw=(j<8)? j : j-1;
        const float* wp = W + ((size_t)(h*16+jw)*9 + c)*2;
        float xrr=Xs[(jj*17+c)*2], xri=Xs[(jj*17+c)*2+1];
        prx = wp[0]*xrr - wp[1]*xri;
        pry = wp[0]*xri + wp[1]*xrr;
      }
      float Vx=prx, Vy=pry;
      if (c==0){
        int jp = (j==0)? 0 : 17-j;
        float ppx=0.f, ppy=0.f;
        if (jp!=8){
          int jw2=(jp<8)? jp : jp-1;
          const float* wp2 = W + ((size_t)(h*16+jw2)*9)*2;
          int jj2=(jp<=8)? jp : jp+15;
          float x2r=Xs[(jj2*17)*2], x2i=Xs[(jj2*17)*2+1];
          ppx = wp2[0]*x2r - wp2[1]*x2i;
          ppy = wp2[0]*x2i + wp2[1]*x2r;
        }
        Vx = 0.5f*(prx + ppx);
        Vy = 0.5f*(pry - ppy);
      }
      float xmr, xmi;
      if (c==0){ xmr=xh0[j].x; xmi=xh0[j].y; }
      else { xmr=Xs[(jj*17+c)*2]; xmi=Xs[(jj*17+c)*2+1]; }
      float zr = a*xmr + Vx;
      float zi = a*xmi + Vy;
      float wf = (side && c!=0)? 2.f : 1.f;
      float* dst = (side? Zk : Zq) + ((size_t)(t*16+h))*306 + m*2;
      dst[0]=wf*zr; dst[1]=wf*zi;
    }
    int b=t>>5, s=t&31;
    float vw=vsw[h], vb=vsb[h], pw=psw[h];
    size_t obase = ((size_t)(b*16+h)*32 + s)*1088;
    for (int e=threadIdx.x;e<544;e+=256){
      int j=e/17, c=e%17;
      float xr=Xs[e*2], xi=Xs[e*2+1];
      float wvr=0.f,wvi=0.f;
      if (c<=8 && (j<8||j>=24)){
        int jw=(j<8)? j : (j-16);
        const float* wv = value_w + ((size_t)(h*16+jw)*9 + c)*2;
        wvr=wv[0]; wvi=wv[1];
      }
      float Mr=xr*wvr-xi*wvi, Mi=xr*wvi+xi*wvr;
      float Mhr=Mr, Mhi=Mi;
      if (c==0){
        float Pr2=0.f,Pi2=0.f;
        int jp2=(j==0)?0:((j==16)?-1:32-j);
        if (jp2>=0 && (jp2<8||jp2>=24)){
          int jw2=(jp2<8)? jp2 : (jp2-16);
          const float* wv2=value_w+((size_t)(h*16+jw2)*9)*2;
          float pxr=Xs[(jp2*17)*2], pxi=Xs[(jp2*17)*2+1];
          Pr2=pxr*wv2[0]-pxi*wv2[1];
          Pi2=pxr*wv2[1]+pxi*wv2[0];
        }
        Mhr=0.5f*(Mr+Pr2); Mhi=0.5f*(Mi-Pi2);
      }
      float Yr=vw*xr+Mhr+((e==0)? vb:0.f);
      float Yi=vw*xi+Mhi;
      const float* pc=proj_w+((size_t)(h*32+j)*17+c)*2;
      float pr=pc[0], pi=pc[1];
      float* o=Yw+obase+e*2;
      o[0]=pr*Yr-pi*Yi+pw*Mr;
      o[1]=pr*Yi+pi*Yr+pw*Mi;
    }
  } else {
    int u=bx-2048;
    int b=u>>8, rem=u&255, t=rem>>3, sg=rem&7;
    float2* xt=(float2*)sh;
    const float2* src = (const float2*)(X64h + ((size_t)(b*32+t))*4224);
    for (int m=threadIdx.x;m<2112;m+=256){
      int r=m/33, c=m%33;
      bool excl = (c<=8) && (r<=8 || r>=56);
      float w = excl? 0.f : ((c==0||c==32)? 1.f : 2.f);
      float2 v = src[m];
      xt[m]=make_float2(v.x*w, v.y*w);
    }
    __syncthreads();
    float acc[4]={0.f,0.f,0.f,0.f};
    const float2* s0=(const float2*)(X64h + ((size_t)(b*32+sg*4))*4224);
    for (int m=threadIdx.x;m<2112;m+=256){
      float2 a2=xt[m];
      #pragma unroll
      for (int j=0;j<4;j++){
        float2 b2=s0[(size_t)j*2112+m];
        acc[j]+=a2.x*b2.x+a2.y*b2.y;
      }
    }
    for (int j=0;j<4;j++){
      float r=block_reduce1(acc[j]);
      if (threadIdx.x==0) Ue[((size_t)(b*32+t))*32 + sg*4+j]=r;
    }
  }
}

// ---- scores + fused softmax, t-split grid (4,16,2) -------------------------
__global__ __launch_bounds__(256) void k_scores2(const float* __restrict__ Zq, const float* __restrict__ Zk,
                          const float* __restrict__ Ue,
                          const float* __restrict__ qsw, const float* __restrict__ qsb,
                          const float* __restrict__ ksw, const float* __restrict__ ksb,
                          float* __restrict__ P){
  int b=blockIdx.x, h=blockIdx.y, tz=blockIdx.z;
  __shared__ float2 zq[16][154];
  __shared__ float2 zk[16][154];
  __shared__ float Pl[16][33];
  for (int i=threadIdx.x;i<16*153;i+=256){
    int t=i/153, m=i%153;
    zq[t][m]=((const float2*)(Zq + ((size_t)((b*32+tz*16+t)*16+h))*306))[m];
  }
  float aq=qsw[h], ak=ksw[h], bq=qsb[h], bk=ksb[h];
  float aqak=aq*ak;
  int tl=threadIdx.x>>4, sl=threadIdx.x&15;
  for (int ch=0; ch<2; ch++){
    __syncthreads();
    for (int i=threadIdx.x;i<16*153;i+=256){
      int s=i/153, m=i%153;
      zk[s][m]=((const float2*)(Zk + ((size_t)((b*32+ch*16+s)*16+h))*306))[m];
    }
    __syncthreads();
    float acc=0.f;
    for (int m=0;m<153;m++){
      float2 a2=zq[tl][m], c2=zk[sl][m];
      acc += a2.x*c2.x + a2.y*c2.y;
    }
    int s=ch*16+sl;
    float G = aqak*Ue[((size_t)(b*32+tz*16+tl))*32+s] + acc;
    Pl[tl][s] = 64.f*(G + bk*zq[tl][0].x + bq*zk[sl][0].x + bq*bk);
  }
  __syncthreads();
  if (threadIdx.x<16){
    int tt=threadIdx.x;
    float mx=-INFINITY;
    for (int s=0;s<32;s++) mx=fmaxf(mx,Pl[tt][s]);
    float e[32]; float sum=0.f;
    for (int s=0;s<32;s++){ e[s]=expf(Pl[tt][s]-mx); sum+=e[s]; }
    float inv=1.f/sum;
    size_t base=((size_t)(b*16+h)*32+tz*16+tt)*32;
    for (int s=0;s<32;s++) P[base+s]=e[s]*inv;
  }
}

// ---- merged SfC2 + skipmix (both consume P, independent) -------------------
__global__ __launch_bounds__(256) void k_SfSk(const float* __restrict__ x, const float* __restrict__ P,
        const float* __restrict__ Yw,
        const float* __restrict__ pw, const float* __restrict__ vw,
        const float* __restrict__ pstat0, const float* __restrict__ n1g, const float* __restrict__ n1b,
        float* __restrict__ Sfp, float* __restrict__ sk){
  __shared__ float sh[4096];
  int bx=blockIdx.x;
  if (bx<272){
    int b=bx/68, rem=bx%68, ec=rem/4, g=rem%4;
    int e0=ec*64, hs0=g*128;
    float (*Pl)[32] = (float(*)[32])sh;
    for (int i=threadIdx.x;i<128*32;i+=256){
      int hsl=i>>5, t=i&31;
      int hs=hs0+hsl, h=hs>>5, s=hs&31;
      Pl[hsl][t]=P[(((size_t)(b*16+h)*32)+t)*32+s];
    }
    __syncthreads();
    int el=threadIdx.x&63, tg=threadIdx.x>>6;
    float acc[8];
    #pragma unroll
    for (int j=0;j<8;j++) acc[j]=0.f;
    const float* Yb = Yw + ((size_t)b*512 + hs0)*1088 + e0 + el;
    #pragma unroll 4
    for (int hsl=0;hsl<128;hsl++){
      float y = Yb[(size_t)hsl*1088];
      #pragma unroll
      for (int j=0;j<8;j++) acc[j] += Pl[hsl][tg*8+j]*y;
    }
    #pragma unroll
    for (int j=0;j<8;j++){
      int t=tg*8+j;
      Sfp[((size_t)(b*32+t)*4+g)*1088 + e0 + el] = acc[j];
    }
  } else {
    int u=bx-272;
    int b=u>>6, rem=u&63, ch=rem>>1, tt=rem&1;
    int pxb=ch*512;
    float* Rs = sh;
    float* cbs = sh+512;
    float* as2 = sh+528;
    float* b0s = sh+560;
    if (threadIdx.x<32){
      float a,b0; affine_from(pstat0, n1g[0], n1b[0], b*32+threadIdx.x, a, b0);
      as2[threadIdx.x]=a; b0s[threadIdx.x]=b0;
    }
    __syncthreads();
    for (int rr=threadIdx.x; rr<512; rr+=256){
      int tl=rr>>5, s=rr&31;
      int t=tt*16+tl;
      float acc=0.f;
      for (int h=0;h<16;h++)
        acc += pw[h]*vw[h]*P[(((size_t)(b*16+h)*32)+t)*32+s];
      Rs[tl*32+s]=acc*as2[s];
      float cb=acc*b0s[s];
      for (int o=16;o>0;o>>=1) cb+=__shfl_down(cb,o,32);
      if (s==0) cbs[tl]=cb;
    }
    __syncthreads();
    float a0[16], a1[16];
    #pragma unroll
    for (int t=0;t<16;t++){ a0[t]=0.f; a1[t]=0.f; }
    for (int s=0;s<32;s++){
      const float* xp = x + ((size_t)(b*32+s))*NPIX + pxb;
      float v0=xp[threadIdx.x], v1=xp[threadIdx.x+256];
      #pragma unroll
      for (int t=0;t<16;t++){ float r=Rs[t*32+s]; a0[t]+=r*v0; a1[t]+=r*v1; }
    }
    #pragma unroll
    for (int t=0;t<16;t++){
      int gt=tt*16+t;
      float cb=cbs[t];
      float* op = sk + ((size_t)(b*32+gt))*NPIX + pxb;
      op[threadIdx.x]=a0[t]+cb; op[threadIdx.x+256]=a1[t]+cb;
    }
  }
}

// ---- merged field0 (blocks 0..2047) + raw spec_z (blocks 2048..2303) -------
__global__ __launch_bounds__(256) void k_f0sp(const float* __restrict__ Sfp,
        const float* __restrict__ sk, const float* __restrict__ x,
        const float* __restrict__ P, const float* __restrict__ X64,
        const float* __restrict__ pstat0,
        const float* __restrict__ n1g, const float* __restrict__ n1b,
        const float* __restrict__ pw, const float* __restrict__ vw,
        const float* __restrict__ psw, const float* __restrict__ vsb, const float* __restrict__ psb,
        float* __restrict__ zf, float* __restrict__ pstatA, float* __restrict__ sp){
  __shared__ float sh[1616];
  int bx=blockIdx.x;
  if (bx<2048){
    int bt=bx>>4, slab=bx&15;
    float* Ss=sh; float* T=sh+1088; float* tw=sh+1360;
    for (int i=threadIdx.x;i<1088;i+=256){
      const float* sp4 = Sfp + (size_t)bt*4352 + i;
      Ss[i] = sp4[0]+sp4[1088]+sp4[2176]+sp4[3264];
    }
    for (int p=threadIdx.x;p<128;p+=256){ float sn,cs; sincosf((2.f*PI_F/128.f)*(float)p,&sn,&cs); tw[p*2]=cs; tw[p*2+1]=sn; }
    __syncthreads();
    int h0 = slab*8;
    for (int e=threadIdx.x;e<136;e+=256){
      int hl=e/17, c=e%17; int h=h0+hl;
      float re=0.f, im=0.f;
      for (int j=0;j<32;j++){
        int r=(j<16)? j : (j+96);
        int p=(r*h)&127;
        float cs=tw[p*2], sn=tw[p*2+1];
        float ar=Ss[(j*17+c)*2], ai=Ss[(j*17+c)*2+1];
        re += ar*cs - ai*sn;
        im += ar*sn + ai*cs;
      }
      T[e*2]=re; T[e*2+1]=im;
    }
    __syncthreads();
    size_t base = (size_t)bt*NPIX + h0*128;
    float Cb = psb[0];
    for (int hh=0;hh<16;hh++) Cb += psw[hh]*vsb[hh];
    float sum=0.f, sq=0.f;
    for (int pos=threadIdx.x;pos<1024;pos+=256){
      int hl=pos>>7, w=pos&127;
      const float* Th=T+hl*17*2;
      float br=tw[w*2], bi=tw[w*2+1];
      float rr=br, ri=bi;
      float v=Th[0];
      for (int c=1;c<17;c++){
        v += 2.f*(Th[c*2]*rr - Th[c*2+1]*ri);
        float nr=rr*br-ri*bi; ri=rr*bi+ri*br; rr=nr;
      }
      float val = v + sk[base+pos] + x[base+pos] + Cb;
      zf[base+pos]=val; sum+=val; sq+=val*val;
    }
    block_reduce2(sum,sq);
    if (threadIdx.x==0){ float* o=pstatA+((size_t)bt*16+slab)*2; o[0]=sum; o[1]=sq; }
  } else {
    int u=bx-2048;
    int bt=u>>1, ec=u&1; int b=bt>>5, t=bt&31;
    float* Sfl=sh; float* Rs=sh+1088;
    if (threadIdx.x<32){
      int s=threadIdx.x; float acc=0.f;
      for (int h=0;h<16;h++)
        acc += pw[h]*vw[h]*P[(((size_t)(b*16+h)*32)+t)*32+s];
      Rs[s]=acc;
    }
    for (int i=threadIdx.x;i<1088;i+=256){
      const float* sp4 = Sfp + (size_t)bt*4352 + i;
      Sfl[i]=sp4[0]+sp4[1088]+sp4[2176]+sp4[3264];
    }
    __syncthreads();
    float a_t,b0_t; affine_from(pstat0,n1g[0],n1b[0],bt,a_t,b0_t);
    float Cb=psb[0];
    for (int h=0;h<16;h++) Cb+=psw[h]*vsb[h];
    float inva=1.f/a_t;
    int e1=ec*272, e2=e1+272;
    for (int e=e1+threadIdx.x;e<e2;e+=256){
      int j=e/17, c=e%17;
      float sr=Sfl[e*2], si=Sfl[e*2+1];
      if (c==0){
        if (j==0){ si=0.f; }
        else if (j==16){ sr*=0.5f; si*=0.5f; }
        else { int jp=32-j; sr=0.5f*(sr+Sfl[jp*34]); si=0.5f*(si-Sfl[jp*34+1]); }
      }
      int i2=(j<16)? j : (j+32);
      float re=0.f, im=0.f;
      const float* xb = X64 + ((size_t)(b*32)*(64*33) + i2*33 + c)*2;
      for (int s=0;s<32;s++){
        const float* xp = xb + (size_t)s*(64*33)*2;
        float r=Rs[s];
        re += r*xp[0]; im += r*xp[1];
      }
      const float* xt = X64 + ((size_t)bt*(64*33) + i2*33 + c)*2;
      re += inva*xt[0]; im += inva*xt[1];
      float zr=sr+re, zi=si+im;
      if (e==0) zr += Cb - b0_t*inva;
      sp[((size_t)bt*544+e)*2]=zr; sp[((size_t)bt*544+e)*2+1]=zi;   // raw spec_z
    }
  }
}

// ---- mixer1 field (16 slabs): fd1 = irfft((a0*spz + d00) * mw1) ------------
__global__ __launch_bounds__(256) void k_field1(const float* __restrict__ sp, const float* __restrict__ wm,
        const float* __restrict__ pstatA,
        const float* __restrict__ ag, const float* __restrict__ n2g, const float* __restrict__ n2b,
        float* __restrict__ fd1, float* __restrict__ pstatB){
  int bt = blockIdx.x, slab = blockIdx.y;
  __shared__ float Ss[1088];
  __shared__ float T[8*17*2];
  __shared__ float tw[128][2];
  float muZ,aA,a0;
  scalA_from(pstatA, ag[0], n2g[0], bt, muZ, aA, a0);
  float d0 = n2b[0] - muZ*a0;
  for (int e=threadIdx.x;e<544;e+=256){
    float xr=a0*sp[((size_t)bt*544+e)*2] + ((e==0)? d0 : 0.f);
    float xi=a0*sp[((size_t)bt*544+e)*2+1];
    float wr=wm[e*2], wi=wm[e*2+1];
    Ss[e*2]=xr*wr-xi*wi; Ss[e*2+1]=xr*wi+xi*wr;
  }
  for (int p=threadIdx.x;p<128;p+=256){ float sn,cs; sincosf((2.f*PI_F/128.f)*(float)p,&sn,&cs); tw[p][0]=cs; tw[p][1]=sn; }
  __syncthreads();
  int h0 = slab*8;
  for (int e=threadIdx.x;e<8*17;e+=256){
    int hl=e/17, c=e%17; int h=h0+hl;
    float re=0.f, im=0.f;
    for (int j=0;j<32;j++){
      int r=(j<16)? j : (j+96);
      int p=(r*h)&127;
      float cs=tw[p][0], sn=tw[p][1];
      float ar=Ss[(j*17+c)*2], ai=Ss[(j*17+c)*2+1];
      re += ar*cs - ai*sn;
      im += ar*sn + ai*cs;
    }
    T[e*2]=re; T[e*2+1]=im;
  }
  __syncthreads();
  size_t base = (size_t)bt*NPIX + h0*128;
  float sum=0.f, sq=0.f;
  for (int pos=threadIdx.x;pos<1024;pos+=256){
    int hl=pos>>7, w=pos&127;
    const float* Th=T+hl*17*2;
    float br=tw[w][0], bi=tw[w][1];
    float rr=br, ri=bi;
    float v=Th[0];
    for (int c=1;c<17;c++){
      v += 2.f*(Th[c*2]*rr - Th[c*2+1]*ri);
      float nr=rr*br-ri*bi; ri=rr*bi+ri*br; rr=nr;
    }
    fd1[base+pos]=v; sum+=v; sq+=v*v;
  }
  block_reduce2(sum,sq);
  if (threadIdx.x==0){ float* o=pstatB+((size_t)bt*16+slab)*2; o[0]=sum; o[1]=sq; }
}

// ---- column DFT of m1 (recomputed on the fly), 16 rows per block -----------
__global__ __launch_bounds__(256) void k_colA1(const float* __restrict__ f1, const float* __restrict__ z,
        const float* __restrict__ pstatA, const float* __restrict__ pstatB,
        const float* __restrict__ ag, const float* __restrict__ n2g, const float* __restrict__ mng1,
        const float* __restrict__ n2b,
        const float* __restrict__ mnb1, const float* __restrict__ msw1, const float* __restrict__ msb1,
        float* __restrict__ A){
  __shared__ float rows[16*128];
  __shared__ float tw[128][2];
  int grow = blockIdx.x*16;
  int t = grow>>7;
  float muZ,aA,a0;
  scalA_from(pstatA, ag[0], n2g[0], t, muZ, aA, a0);
  float b2 = n2b[0];
  float mu1,c1;
  scalB_from(pstatB, mng1[0], t, mu1, c1);
  float nb=mnb1[0], sw=msw1[0], sb=msb1[0];
  for (int i=threadIdx.x;i<2048;i+=256){
    size_t gi=(size_t)grow*128+i;
    float m0v=(z[gi]-muZ)*a0+b2;
    float y=(f1[gi]-mu1)*c1+nb + m0v*sw + sb;
    rows[i]=gelu_f(y);
  }
  for (int p=threadIdx.x;p<128;p+=256){ float sn,cs; sincosf(-(2.f*PI_F/128.f)*(float)p,&sn,&cs); tw[p][0]=cs; tw[p][1]=sn; }
  __syncthreads();
  for (int e=threadIdx.x;e<16*17;e+=256){
    int r=e/17, c=e%17;
    const float* rp=rows+r*128;
    float re=0.f, im=0.f;
    for (int w=0;w<128;w++){
      int p=(c*w)&127;
      float v=rp[w];
      re+=v*tw[p][0]; im+=v*tw[p][1];
    }
    float* o=A+((size_t)(grow+r)*17+c)*2; o[0]=re; o[1]=im;
  }
}

// ---- forward 32x17 modes, column-group parallel ----------------------------
__global__ __launch_bounds__(256) void k_rowfft32(const float* __restrict__ A, float* __restrict__ spec){
  int s=blockIdx.x, cg2=blockIdx.y;
  int c0 = (cg2==0)? 0 : (1+cg2*4);
  int nc = (cg2==0)? 5 : 4;
  __shared__ float a[128*5*2];
  __shared__ float tw[128][2];
  for (int i=threadIdx.x;i<128*nc*2;i+=256){
    int r=i/(2*nc), q=i%(2*nc);
    a[(r*5+(q>>1))*2+(q&1)] = A[((size_t)(s*128+r)*17 + c0)*2 + q];
  }
  for (int p=threadIdx.x;p<128;p+=256){ float sn,cs; sincosf(-(2.f*PI_F/128.f)*(float)p,&sn,&cs); tw[p][0]=cs; tw[p][1]=sn; }
  __syncthreads();
  const float sc=1.f/16384.f;
  for (int e=threadIdx.x;e<32*nc;e+=256){
    int j=e/nc, cl=e%nc;
    int r=(j<16)? j : (j+96);
    float re=0.f,im=0.f;
    for (int h=0;h<128;h++){
      int p=(r*h)&127;
      float cs=tw[p][0], sn=tw[p][1];
      float ar=a[(h*5+cl)*2], ai=a[(h*5+cl)*2+1];
      re += ar*cs - ai*sn;
      im += ar*sn + ai*cs;
    }
    float* o=spec+((size_t)s*544 + j*17 + c0+cl)*2;
    o[0]=re*sc; o[1]=im*sc;
  }
}

// ---- mixer2 field (16 slabs): fd2 = irfft(sp2 * mw2); cross-moment stats ---
__global__ __launch_bounds__(256) void k_field2(const float* __restrict__ sp2, const float* __restrict__ wm,
        const float* __restrict__ f1, const float* __restrict__ z,
        const float* __restrict__ pstatA, const float* __restrict__ pstatB,
        const float* __restrict__ ag, const float* __restrict__ n2g, const float* __restrict__ mng1,
        const float* __restrict__ n2b, const float* __restrict__ mnb1,
        const float* __restrict__ msw1, const float* __restrict__ msb1,
        float* __restrict__ fd2, float* __restrict__ pstatC){
  int bt = blockIdx.x, slab = blockIdx.y;
  __shared__ float Ss[1088];
  __shared__ float T[8*17*2];
  __shared__ float tw[128][2];
  for (int e=threadIdx.x;e<544;e+=256){
    float xr=sp2[((size_t)bt*544+e)*2], xi=sp2[((size_t)bt*544+e)*2+1];
    float wr=wm[e*2], wi=wm[e*2+1];
    Ss[e*2]=xr*wr-xi*wi; Ss[e*2+1]=xr*wi+xi*wr;
  }
  for (int p=threadIdx.x;p<128;p+=256){ float sn,cs; sincosf((2.f*PI_F/128.f)*(float)p,&sn,&cs); tw[p][0]=cs; tw[p][1]=sn; }
  __syncthreads();
  int h0 = slab*8;
  for (int e=threadIdx.x;e<8*17;e+=256){
    int hl=e/17, c=e%17; int h=h0+hl;
    float re=0.f, im=0.f;
    for (int j=0;j<32;j++){
      int r=(j<16)? j : (j+96);
      int p=(r*h)&127;
      float cs=tw[p][0], sn=tw[p][1];
      float ar=Ss[(j*17+c)*2], ai=Ss[(j*17+c)*2+1];
      re += ar*cs - ai*sn;
      im += ar*sn + ai*cs;
    }
    T[e*2]=re; T[e*2+1]=im;
  }
  __syncthreads();
  size_t base = (size_t)bt*NPIX + h0*128;
  float muZ,aA,a0,mu1,c1;
  scalA_from(pstatA, ag[0], n2g[0], bt, muZ, aA, a0);
  scalB_from(pstatB, mng1[0], bt, mu1, c1);
  float b2=n2b[0], nb1=mnb1[0], sw1=msw1[0], sb1=msb1[0];
  float s_f=0.f,s_fsq=0.f,s_m=0.f,s_msq=0.f,s_x=0.f;
  for (int pos=threadIdx.x;pos<1024;pos+=256){
    int hl=pos>>7, w=pos&127;
    const float* Th=T+hl*17*2;
    float br=tw[w][0], bi=tw[w][1];
    float rr=br, ri=bi;
    float v=Th[0];
    for (int c=1;c<17;c++){
      v += 2.f*(Th[c*2]*rr - Th[c*2+1]*ri);
      float nr=rr*br-ri*bi; ri=rr*bi+ri*br; rr=nr;
    }
    size_t gi=base+pos;
    float m0v=(z[gi]-muZ)*a0+b2;
    float y=(f1[gi]-mu1)*c1+nb1 + m0v*sw1 + sb1;
    float m1v=gelu_f(y);
    fd2[gi]=v;
    s_f+=v; s_fsq+=v*v; s_m+=m1v; s_msq+=m1v*m1v; s_x+=v*m1v;
  }
  block_reduce2(s_f,s_fsq);
  block_reduce2(s_m,s_msq);
  s_x = block_reduce1(s_x);
  if (threadIdx.x==0){
    float* o=pstatC+((size_t)bt*16+slab)*5;
    o[0]=s_f; o[1]=s_fsq; o[2]=s_m; o[3]=s_msq; o[4]=s_x;
  }
}

// ---- final (16 slabs): out = norm(m2)+a2, scalars inline -------------------
__global__ __launch_bounds__(256) void k_final2(const float* __restrict__ z, const float* __restrict__ f1,
        const float* __restrict__ f2,
        const float* __restrict__ pstatA, const float* __restrict__ pstatB, const float* __restrict__ pstatC,
        const float* __restrict__ ag, const float* __restrict__ n2g, const float* __restrict__ mng1,
        const float* __restrict__ mng2, const float* __restrict__ outg,
        const float* __restrict__ ab, const float* __restrict__ n2b,
        const float* __restrict__ mnb1, const float* __restrict__ msw1, const float* __restrict__ msb1,
        const float* __restrict__ mnb2, const float* __restrict__ msw2, const float* __restrict__ msb2,
        const float* __restrict__ outb, float* __restrict__ out){
  int bt=blockIdx.x, slab=blockIdx.y;
  float muZ,aA,a0,mu1,c1,mu2f,c2,mu3,c3;
  scalA_from(pstatA, ag[0], n2g[0], bt, muZ, aA, a0);
  scalB_from(pstatB, mng1[0], bt, mu1, c1);
  float sw2=msw2[0], K=mnb2[0]+msb2[0];
  scalC_from(pstatC, mng2[0], K, sw2, outg[0], bt, mu2f, c2, mu3, c3);
  float b1=ab[0], b2=n2b[0], nb1=mnb1[0], sw1=msw1[0], sb1=msb1[0];
  float nb2=mnb2[0], sb2=msb2[0], bo=outb[0];
  size_t base=(size_t)bt*NPIX + (size_t)slab*1024;
  for (int i=threadIdx.x;i<1024;i+=256){
    size_t gi=base+i;
    float zv=z[gi];
    float m0v=(zv-muZ)*a0+b2;
    float a2v=(zv-muZ)*aA+b1;
    float y=(f1[gi]-mu1)*c1+nb1 + m0v*sw1 + sb1;
    float m1v=gelu_f(y);
    float m2v=(f2[gi]-mu2f)*c2+nb2 + m1v*sw2 + sb2;
    out[gi]=(m2v-mu3)*c3+bo+a2v;
  }
}

extern "C" void kernel_launch(void* const* d_in, const int* in_sizes, int n_in,
                              void* d_out, int out_size, void* d_ws, size_t ws_size,
                              hipStream_t stream){
  const float* x        = (const float*)d_in[0];
  const float* key_w    = (const float*)d_in[1];
  const float* key_sw   = (const float*)d_in[2];
  const float* key_sb   = (const float*)d_in[3];
  const float* query_w  = (const float*)d_in[4];
  const float* query_sw = (const float*)d_in[5];
  const float* query_sb = (const float*)d_in[6];
  const float* value_w  = (const float*)d_in[7];
  const float* value_sw = (const float*)d_in[8];
  const float* value_sb = (const float*)d_in[9];
  const float* proj_w   = (const float*)d_in[10];
  const float* proj_sw  = (const float*)d_in[11];
  const float* proj_sb  = (const float*)d_in[12];
  const float* norm1_g  = (const float*)d_in[13];
  const float* norm1_b  = (const float*)d_in[14];
  const float* attn_g   = (const float*)d_in[15];
  const float* attn_b   = (const float*)d_in[16];
  const float* norm2_g  = (const float*)d_in[17];
  const float* norm2_b  = (const float*)d_in[18];
  const float* mw1      = (const float*)d_in[19];
  const float* msw1     = (const float*)d_in[20];
  const float* msb1     = (const float*)d_in[21];
  const float* mng1     = (const float*)d_in[22];
  const float* mnb1     = (const float*)d_in[23];
  const float* mw2      = (const float*)d_in[24];
  const float* msw2     = (const float*)d_in[25];
  const float* msb2     = (const float*)d_in[26];
  const float* mng2     = (const float*)d_in[27];
  const float* mnb2     = (const float*)d_in[28];
  const float* outg     = (const float*)d_in[29];
  const float* outb     = (const float*)d_in[30];
  float* out = (float*)d_out;
  float* ws  = (float*)d_ws;

  size_t off=0;
  float* A   = ws + off; off += (size_t)128*128*33*2;
  float* X64 = ws + off; off += (size_t)128*64*33*2;
  float* X64h= ws + off; off += (size_t)128*64*33*2;
  float* Zq  = ws + off; off += (size_t)128*16*306;
  float* Zk  = ws + off; off += (size_t)128*16*306;
  float* Ue  = ws + off; off += (size_t)4*32*32;
  float* P   = ws + off; off += (size_t)4*16*32*32;
  float* Yw  = ws + off; off += (size_t)2048*1088;
  float* Sfp = ws + off; off += (size_t)128*4*1088;
  float* sk  = ws + off; off += (size_t)128*16384;
  float* zf  = ws + off; off += (size_t)128*16384;
  float* fd1 = ws + off; off += (size_t)128*16384;
  float* fd2 = ws + off; off += (size_t)128*16384;
  float* sp  = ws + off; off += (size_t)128*544*2;
  float* sp2 = ws + off; off += (size_t)128*544*2;
  float* pstat0 = ws + off; off += (size_t)128*8*2;
  float* pstatA = ws + off; off += (size_t)128*16*2;
  float* pstatB = ws + off; off += (size_t)128*16*2;
  float* pstatC = ws + off; off += (size_t)128*16*5;

  k_scol<<<2048,256,0,stream>>>(x, A, pstat0);
  k_rowfft64<<<dim3(128,3),256,0,stream>>>(A, pstat0, norm1_g, norm1_b, X64, X64h);
  k_UeZYw<<<3072,256,0,stream>>>(X64, X64h, query_w, query_sw, key_w, key_sw,
      value_w, value_sw, value_sb, proj_w, proj_sw, Zq, Zk, Yw, Ue);
  k_scores2<<<dim3(4,16,2),256,0,stream>>>(Zq, Zk, Ue, query_sw, query_sb, key_sw, key_sb, P);
  k_SfSk<<<528,256,0,stream>>>(x, P, Yw, proj_sw, value_sw, pstat0, norm1_g, norm1_b, Sfp, sk);
  k_f0sp<<<2304,256,0,stream>>>(Sfp, sk, x, P, X64, pstat0, norm1_g, norm1_b,
      proj_sw, value_sw, proj_sw, value_sb, proj_sb, zf, pstatA, sp);
  k_field1<<<dim3(128,16),256,0,stream>>>(sp, mw1, pstatA, attn_g, norm2_g, norm2_b, fd1, pstatB);
  k_colA1<<<1024,256,0,stream>>>(fd1, zf, pstatA, pstatB, attn_g, norm2_g, mng1,
      norm2_b, mnb1, msw1, msb1, A);
  k_rowfft32<<<dim3(128,4),256,0,stream>>>(A, sp2);
  k_field2<<<dim3(128,16),256,0,stream>>>(sp2, mw2, fd1, zf, pstatA, pstatB,
      attn_g, norm2_g, mng1, norm2_b, mnb1, msw1, msb1, fd2, pstatC);
  k_final2<<<dim3(128,16),256,0,stream>>>(zf, fd1, fd2, pstatA, pstatB, pstatC,
      attn_g, norm2_g, mng1, mng2, outg, attn_b, norm2_b,
      mnb1, msw1, msb1, mnb2, msw2, msb2, outb, out);
}